// Round 1
// baseline (173.034 us; speedup 1.0000x reference)
//
#include <hip/hip_runtime.h>
#include <math.h>

typedef _Float16 f16;
typedef _Float16 f16x8 __attribute__((ext_vector_type(8)));
typedef _Float16 f16x4 __attribute__((ext_vector_type(4)));
typedef float f32x4 __attribute__((ext_vector_type(4)));

#define LOG2E 1.44269504088896340736f

static constexpr int Bb = 2;      // batch
static constexpr int Ls = 2048;   // seqlen
static constexpr int Dm = 2048;   // d_inner
static constexpr int Ns = 16;     // d_state
static constexpr int Rr = 128;    // dt_rank
static constexpr int Mm = Bb * Ls;   // 4096 rows (b*l)
static constexpr int NC = 32;        // scan chunks
static constexpr int LC = Ls / NC;   // 64 steps per chunk
static constexpr int SK = 4;         // split-K for GEMM1
static constexpr int KC = Dm / SK;   // 512

// ---------------- prep: dt_proj_w -> fp16, A2 = -exp(A_log)*log2(e) ----------
__global__ __launch_bounds__(256) void k_prep(const float* __restrict__ dtw,
                                              const float* __restrict__ alog,
                                              f16* __restrict__ dtw16,
                                              float* __restrict__ a2) {
    int i = blockIdx.x * 256 + threadIdx.x;
    if (i < Dm * Rr) dtw16[i] = (f16)dtw[i];
    if (i < Dm * Ns) a2[i] = -expf(alog[i]) * LOG2E;
}

// ---------------- GEMM1: x_dbl partials, split-K ----------------------------
// P[sk][m][c], m<4096, c<160
__global__ __launch_bounds__(256) void k_gemm1(const float* __restrict__ x,
                                               const float* __restrict__ w,
                                               float* __restrict__ P) {
    __shared__ f16 Af[64 * 40];    // 64 rows, stride 40 f16 = 80B (pad kills conflicts)
    __shared__ f16 Bf[160 * 40];
    const int tid = threadIdx.x;
    const int m0 = blockIdx.x * 64;
    const int sk = blockIdx.y;
    const int kbase = sk * KC;
    const int lane = tid & 63;
    const int wv = tid >> 6;
    const int col = lane & 15;
    const int kg = lane >> 4;

    f32x4 acc[10];
#pragma unroll
    for (int i = 0; i < 10; i++) acc[i] = (f32x4){0.f, 0.f, 0.f, 0.f};

    for (int ks = 0; ks < KC / 32; ks++) {
        const int kb = kbase + ks * 32;
        if (ks) __syncthreads();
        // stage A tile 64x32 (f32 -> f16)
#pragma unroll
        for (int j = 0; j < 2; j++) {
            int f = tid + j * 256;            // 512 float4
            int m = f >> 3, kq = f & 7;
            float4 v = *(const float4*)(x + (size_t)(m0 + m) * Dm + kb + kq * 4);
            f16x4 h = {(f16)v.x, (f16)v.y, (f16)v.z, (f16)v.w};
            *(f16x4*)((char*)Af + m * 80 + kq * 8) = h;
        }
        // stage B tile 160x32
#pragma unroll
        for (int j = 0; j < 5; j++) {
            int f = tid + j * 256;            // 1280 float4
            int n = f >> 3, kq = f & 7;
            float4 v = *(const float4*)(w + (size_t)n * Dm + kb + kq * 4);
            f16x4 h = {(f16)v.x, (f16)v.y, (f16)v.z, (f16)v.w};
            *(f16x4*)((char*)Bf + n * 80 + kq * 8) = h;
        }
        __syncthreads();
        f16x8 a = *(const f16x8*)((char*)Af + (wv * 16 + col) * 80 + kg * 16);
#pragma unroll
        for (int nf = 0; nf < 10; nf++) {
            f16x8 b = *(const f16x8*)((char*)Bf + (nf * 16 + col) * 80 + kg * 16);
            acc[nf] = __builtin_amdgcn_mfma_f32_16x16x32_f16(a, b, acc[nf], 0, 0, 0);
        }
    }
    float* Pb = P + (size_t)sk * Mm * 160 + (size_t)m0 * 160;
#pragma unroll
    for (int nf = 0; nf < 10; nf++)
#pragma unroll
        for (int r = 0; r < 4; r++) {
            int row = wv * 16 + kg * 4 + r;
            Pb[(size_t)row * 160 + nf * 16 + col] = acc[nf][r];
        }
}

// ---------------- reduce split-K, pack delta_un (fp16) / Bm / Cm ------------
__global__ __launch_bounds__(256) void k_red1(const float* __restrict__ P,
                                              f16* __restrict__ dun,
                                              float* __restrict__ Bm,
                                              float* __restrict__ Cm) {
    int e = blockIdx.x * 256 + threadIdx.x;   // < 4096*160
    int m = e / 160, c = e % 160;
    float v = 0.f;
#pragma unroll
    for (int s = 0; s < SK; s++) v += P[(size_t)s * Mm * 160 + e];
    if (c < 128)      dun[(size_t)m * Rr + c] = (f16)v;
    else if (c < 144) Bm[(size_t)m * 16 + (c - 128)] = v;
    else              Cm[(size_t)m * 16 + (c - 144)] = v;
}

// ---------------- GEMM2: delta = softplus(dun . dtw^T + b) ------------------
__global__ __launch_bounds__(256) void k_gemm2(const f16* __restrict__ dun,
                                               const f16* __restrict__ dtw16,
                                               const float* __restrict__ bias,
                                               float* __restrict__ delta) {
    __shared__ f16 Ad[64 * 128];   // XOR-swizzled
    __shared__ f16 Bd[128 * 128];
    const int tid = threadIdx.x;
    const int lane = tid & 63;
    const int wv = tid >> 6;
    const int m0 = blockIdx.x * 64;
    const int n0 = blockIdx.y * 128;
    const int col = lane & 15;
    const int kg = lane >> 4;
    const int wm = wv & 1, wn = wv >> 1;

    const uint4* gA = (const uint4*)(dun + (size_t)m0 * Rr);
#pragma unroll
    for (int j = 0; j < 4; j++) {
        int slot = tid + j * 256;            // 1024 x 16B
        uint4 v = gA[slot];
        int off = slot * 16;
        int row = slot >> 4;
        *(uint4*)((char*)Ad + (off ^ ((row & 7) << 4))) = v;
    }
    const uint4* gB = (const uint4*)(dtw16 + (size_t)n0 * Rr);
#pragma unroll
    for (int j = 0; j < 8; j++) {
        int slot = tid + j * 256;            // 2048 x 16B
        uint4 v = gB[slot];
        int off = slot * 16;
        int row = slot >> 4;
        *(uint4*)((char*)Bd + (off ^ ((row & 7) << 4))) = v;
    }
    __syncthreads();

    f32x4 acc[2][4];
#pragma unroll
    for (int i = 0; i < 2; i++)
#pragma unroll
        for (int j = 0; j < 4; j++) acc[i][j] = (f32x4){0.f, 0.f, 0.f, 0.f};

#pragma unroll
    for (int ks = 0; ks < 4; ks++) {
        f16x8 a[2], b[4];
#pragma unroll
        for (int mf = 0; mf < 2; mf++) {
            int row = wm * 32 + mf * 16 + col;
            int off = (row << 8) + ks * 64 + kg * 16;
            a[mf] = *(const f16x8*)((char*)Ad + (off ^ ((row & 7) << 4)));
        }
#pragma unroll
        for (int nf = 0; nf < 4; nf++) {
            int row = wn * 64 + nf * 16 + col;
            int off = (row << 8) + ks * 64 + kg * 16;
            b[nf] = *(const f16x8*)((char*)Bd + (off ^ ((row & 7) << 4)));
        }
#pragma unroll
        for (int mf = 0; mf < 2; mf++)
#pragma unroll
            for (int nf = 0; nf < 4; nf++)
                acc[mf][nf] = __builtin_amdgcn_mfma_f32_16x16x32_f16(a[mf], b[nf], acc[mf][nf], 0, 0, 0);
    }
#pragma unroll
    for (int mf = 0; mf < 2; mf++)
#pragma unroll
        for (int nf = 0; nf < 4; nf++) {
            int gd = n0 + wn * 64 + nf * 16 + col;
            float bv = bias[gd];
#pragma unroll
            for (int r = 0; r < 4; r++) {
                int gm = m0 + wm * 32 + mf * 16 + kg * 4 + r;
                float v = acc[mf][nf][r] + bv;
                float sp = (v > 15.f) ? v : log1pf(expf(v));
                delta[(size_t)gm * Dm + gd] = sp;
            }
        }
}

// ---------------- scan helpers ----------------------------------------------
#define UPD(q, bv)                                                   \
    s[q * 4 + 0] = fmaf(exp2f(dc * a2[q * 4 + 0]), s[q * 4 + 0], dx * bv.x); \
    s[q * 4 + 1] = fmaf(exp2f(dc * a2[q * 4 + 1]), s[q * 4 + 1], dx * bv.y); \
    s[q * 4 + 2] = fmaf(exp2f(dc * a2[q * 4 + 2]), s[q * 4 + 2], dx * bv.z); \
    s[q * 4 + 3] = fmaf(exp2f(dc * a2[q * 4 + 3]), s[q * 4 + 3], dx * bv.w);

#define DOT(q, cv)                                \
    ya = fmaf(s[q * 4 + 0], cv.x, ya);            \
    yb = fmaf(s[q * 4 + 1], cv.y, yb);            \
    yc = fmaf(s[q * 4 + 2], cv.z, yc);            \
    yd = fmaf(s[q * 4 + 3], cv.w, yd);

// ---------------- scan phase 1: chunk summaries -----------------------------
// Ap/Sl layout: [b][c][d][n]
__global__ __launch_bounds__(256) void k_scan1(const float* __restrict__ delta,
                                               const float* __restrict__ x,
                                               const float* __restrict__ Bm,
                                               const float* __restrict__ a2g,
                                               float* __restrict__ Ap,
                                               float* __restrict__ Sl) {
    __shared__ float Bl[LC * 16];
    const int tid = threadIdx.x;
    const int d = blockIdx.x * 256 + tid;
    const int c = blockIdx.y;
    const int b = blockIdx.z;
    const int l0 = c * LC;

    ((float4*)Bl)[tid] = ((const float4*)(Bm + (size_t)(b * Ls + l0) * 16))[tid];

    float a2[16];
    {
        const float4* ap = (const float4*)(a2g + d * 16);
        float4 t0 = ap[0], t1 = ap[1], t2 = ap[2], t3 = ap[3];
        a2[0]=t0.x; a2[1]=t0.y; a2[2]=t0.z; a2[3]=t0.w;
        a2[4]=t1.x; a2[5]=t1.y; a2[6]=t1.z; a2[7]=t1.w;
        a2[8]=t2.x; a2[9]=t2.y; a2[10]=t2.z; a2[11]=t2.w;
        a2[12]=t3.x; a2[13]=t3.y; a2[14]=t3.z; a2[15]=t3.w;
    }
    float s[16];
#pragma unroll
    for (int n = 0; n < 16; n++) s[n] = 0.f;
    float dsum = 0.f;

    __syncthreads();

    const float* dptr = delta + (size_t)(b * Ls + l0) * Dm + d;
    const float* xptr = x + (size_t)(b * Ls + l0) * Dm + d;
    const float4* Bl4 = (const float4*)Bl;

    float dc = dptr[0], xc = xptr[0];
    float4 b0 = Bl4[0], b1 = Bl4[1], b2 = Bl4[2], b3 = Bl4[3];

    for (int i = 0; i < LC; i++) {
        int in_ = (i + 1 < LC) ? i + 1 : i;
        float dn_ = dptr[(size_t)in_ * Dm];
        float xn_ = xptr[(size_t)in_ * Dm];
        float4 nb0 = Bl4[in_ * 4 + 0], nb1 = Bl4[in_ * 4 + 1];
        float4 nb2 = Bl4[in_ * 4 + 2], nb3 = Bl4[in_ * 4 + 3];
        float dx = dc * xc;
        dsum += dc;
        UPD(0, b0) UPD(1, b1) UPD(2, b2) UPD(3, b3)
        dc = dn_; xc = xn_;
        b0 = nb0; b1 = nb1; b2 = nb2; b3 = nb3;
    }

    size_t o = ((size_t)(b * NC + c) * Dm + d) * 16;
#pragma unroll
    for (int q = 0; q < 4; q++) {
        float4 apv = make_float4(exp2f(dsum * a2[q * 4 + 0]), exp2f(dsum * a2[q * 4 + 1]),
                                 exp2f(dsum * a2[q * 4 + 2]), exp2f(dsum * a2[q * 4 + 3]));
        float4 slv = make_float4(s[q * 4 + 0], s[q * 4 + 1], s[q * 4 + 2], s[q * 4 + 3]);
        *(float4*)(Ap + o + q * 4) = apv;
        *(float4*)(Sl + o + q * 4) = slv;
    }
}

// ---------------- scan phase 2: sequential chunk combine --------------------
__global__ __launch_bounds__(256) void k_scan2(const float* __restrict__ Ap,
                                               const float* __restrict__ Sl,
                                               float* __restrict__ S0) {
    int e = blockIdx.x * 256 + threadIdx.x;   // < Bb*Dm*16
    int b = e >> 15;
    int rem = e & 32767;
    int d = rem >> 4;
    int n = rem & 15;
    float s = 0.f;
    for (int c = 0; c < NC; c++) {
        size_t o = ((size_t)(b * NC + c) * Dm + d) * 16 + n;
        S0[o] = s;
        s = fmaf(Ap[o], s, Sl[o]);
    }
}

// ---------------- scan phase 3: recompute with true init, emit y ------------
__global__ __launch_bounds__(256) void k_scan3(const float* __restrict__ delta,
                                               const float* __restrict__ x,
                                               const float* __restrict__ Bm,
                                               const float* __restrict__ Cm,
                                               const float* __restrict__ a2g,
                                               const float* __restrict__ S0,
                                               const float* __restrict__ Dpar,
                                               float* __restrict__ out) {
    __shared__ float Bl[LC * 16];
    __shared__ float Cl[LC * 16];
    const int tid = threadIdx.x;
    const int d = blockIdx.x * 256 + tid;
    const int c = blockIdx.y;
    const int b = blockIdx.z;
    const int l0 = c * LC;

    ((float4*)Bl)[tid] = ((const float4*)(Bm + (size_t)(b * Ls + l0) * 16))[tid];
    ((float4*)Cl)[tid] = ((const float4*)(Cm + (size_t)(b * Ls + l0) * 16))[tid];

    float a2[16];
    {
        const float4* ap = (const float4*)(a2g + d * 16);
        float4 t0 = ap[0], t1 = ap[1], t2 = ap[2], t3 = ap[3];
        a2[0]=t0.x; a2[1]=t0.y; a2[2]=t0.z; a2[3]=t0.w;
        a2[4]=t1.x; a2[5]=t1.y; a2[6]=t1.z; a2[7]=t1.w;
        a2[8]=t2.x; a2[9]=t2.y; a2[10]=t2.z; a2[11]=t2.w;
        a2[12]=t3.x; a2[13]=t3.y; a2[14]=t3.z; a2[15]=t3.w;
    }
    size_t o = ((size_t)(b * NC + c) * Dm + d) * 16;
    float s[16];
    {
        const float4* sp = (const float4*)(S0 + o);
        float4 t0 = sp[0], t1 = sp[1], t2 = sp[2], t3 = sp[3];
        s[0]=t0.x; s[1]=t0.y; s[2]=t0.z; s[3]=t0.w;
        s[4]=t1.x; s[5]=t1.y; s[6]=t1.z; s[7]=t1.w;
        s[8]=t2.x; s[9]=t2.y; s[10]=t2.z; s[11]=t2.w;
        s[12]=t3.x; s[13]=t3.y; s[14]=t3.z; s[15]=t3.w;
    }
    float Dp = Dpar[d];

    __syncthreads();

    const float* dptr = delta + (size_t)(b * Ls + l0) * Dm + d;
    const float* xptr = x + (size_t)(b * Ls + l0) * Dm + d;
    float* optr = out + (size_t)(b * Ls + l0) * Dm + d;
    const float4* Bl4 = (const float4*)Bl;
    const float4* Cl4 = (const float4*)Cl;

    float dc = dptr[0], xc = xptr[0];
    float4 b0 = Bl4[0], b1 = Bl4[1], b2 = Bl4[2], b3 = Bl4[3];
    float4 c0 = Cl4[0], c1 = Cl4[1], c2 = Cl4[2], c3 = Cl4[3];

    for (int i = 0; i < LC; i++) {
        int in_ = (i + 1 < LC) ? i + 1 : i;
        float dn_ = dptr[(size_t)in_ * Dm];
        float xn_ = xptr[(size_t)in_ * Dm];
        float4 nb0 = Bl4[in_ * 4 + 0], nb1 = Bl4[in_ * 4 + 1];
        float4 nb2 = Bl4[in_ * 4 + 2], nb3 = Bl4[in_ * 4 + 3];
        float4 nc0 = Cl4[in_ * 4 + 0], nc1 = Cl4[in_ * 4 + 1];
        float4 nc2 = Cl4[in_ * 4 + 2], nc3 = Cl4[in_ * 4 + 3];

        float dx = dc * xc;
        UPD(0, b0) UPD(1, b1) UPD(2, b2) UPD(3, b3)
        float ya = 0.f, yb = 0.f, yc = 0.f, yd = 0.f;
        DOT(0, c0) DOT(1, c1) DOT(2, c2) DOT(3, c3)
        optr[(size_t)i * Dm] = fmaf(xc, Dp, (ya + yb) + (yc + yd));

        dc = dn_; xc = xn_;
        b0 = nb0; b1 = nb1; b2 = nb2; b3 = nb3;
        c0 = nc0; c1 = nc1; c2 = nc2; c3 = nc3;
    }
}

// ---------------- host launcher ---------------------------------------------
extern "C" void kernel_launch(void* const* d_in, const int* in_sizes, int n_in,
                              void* d_out, int out_size, void* d_ws, size_t ws_size,
                              hipStream_t stream) {
    const float* x    = (const float*)d_in[0];
    const float* xw   = (const float*)d_in[1];
    const float* dtw  = (const float*)d_in[2];
    const float* dtb  = (const float*)d_in[3];
    const float* alog = (const float*)d_in[4];
    const float* dpar = (const float*)d_in[5];
    float* out = (float*)d_out;

    char* ws = (char*)d_ws;
    size_t off = 0;
    auto alloc = [&](size_t bytes) {
        char* p = ws + off;
        off += (bytes + 255) & ~(size_t)255;
        return p;
    };
    f16*   dun    = (f16*)  alloc((size_t)Mm * Rr * 2);           // 1 MB
    float* BmA    = (float*)alloc((size_t)Mm * 16 * 4);           // 256 KB
    float* CmA    = (float*)alloc((size_t)Mm * 16 * 4);           // 256 KB
    float* Pp     = (float*)alloc((size_t)SK * Mm * 160 * 4);     // 10.5 MB
    float* deltaA = (float*)alloc((size_t)Mm * Dm * 4);           // 33.5 MB
    float* ApA    = (float*)alloc((size_t)Bb * NC * Dm * 16 * 4); // 8 MB
    float* SlA    = (float*)alloc((size_t)Bb * NC * Dm * 16 * 4); // 8 MB
    float* S0A    = (float*)alloc((size_t)Bb * NC * Dm * 16 * 4); // 8 MB
    f16*   dtw16  = (f16*)  alloc((size_t)Dm * Rr * 2);           // 512 KB
    float* a2A    = (float*)alloc((size_t)Dm * Ns * 4);           // 128 KB

    hipLaunchKernelGGL(k_prep, dim3((Dm * Rr) / 256), dim3(256), 0, stream,
                       dtw, alog, dtw16, a2A);
    hipLaunchKernelGGL(k_gemm1, dim3(Mm / 64, SK), dim3(256), 0, stream, x, xw, Pp);
    hipLaunchKernelGGL(k_red1, dim3((Mm * 160) / 256), dim3(256), 0, stream,
                       Pp, dun, BmA, CmA);
    hipLaunchKernelGGL(k_gemm2, dim3(Mm / 64, Dm / 128), dim3(256), 0, stream,
                       dun, dtw16, dtb, deltaA);
    hipLaunchKernelGGL(k_scan1, dim3(Dm / 256, NC, Bb), dim3(256), 0, stream,
                       deltaA, x, BmA, a2A, ApA, SlA);
    hipLaunchKernelGGL(k_scan2, dim3((Bb * Dm * 16) / 256), dim3(256), 0, stream,
                       ApA, SlA, S0A);
    hipLaunchKernelGGL(k_scan3, dim3(Dm / 256, NC, Bb), dim3(256), 0, stream,
                       deltaA, x, BmA, CmA, a2A, S0A, dpar, out);
}

// Round 2
// 167.461 us; speedup vs baseline: 1.0333x; 1.0333x over previous
//
#include <hip/hip_runtime.h>
#include <math.h>

typedef _Float16 f16;
typedef _Float16 f16x8 __attribute__((ext_vector_type(8)));
typedef _Float16 f16x4 __attribute__((ext_vector_type(4)));
typedef float f32x4 __attribute__((ext_vector_type(4)));

#define LOG2E 1.44269504088896340736f

static constexpr int Bb = 2;      // batch
static constexpr int Ls = 2048;   // seqlen
static constexpr int Dm = 2048;   // d_inner
static constexpr int Ns = 16;     // d_state
static constexpr int Rr = 128;    // dt_rank
static constexpr int Mm = Bb * Ls;   // 4096 rows (b*l)
static constexpr int NC = 64;        // scan chunks
static constexpr int LC = Ls / NC;   // 32 steps per chunk
static constexpr int SK = 4;         // split-K for GEMM1
static constexpr int KC = Dm / SK;   // 512

// ---------------- prep: dt_proj_w -> fp16, A2[n][d] = -exp(A_log)*log2e -----
__global__ __launch_bounds__(256) void k_prep(const float* __restrict__ dtw,
                                              const float* __restrict__ alog,
                                              f16* __restrict__ dtw16,
                                              float* __restrict__ a2) {
    int i = blockIdx.x * 256 + threadIdx.x;
    if (i < Dm * Rr) dtw16[i] = (f16)dtw[i];
    if (i < Dm * Ns) {
        int d = i >> 4, n = i & 15;
        a2[n * Dm + d] = -expf(alog[i]) * LOG2E;
    }
}

// ---------------- GEMM1: x_dbl partials, split-K ----------------------------
__global__ __launch_bounds__(256) void k_gemm1(const float* __restrict__ x,
                                               const float* __restrict__ w,
                                               float* __restrict__ P) {
    __shared__ f16 Af[64 * 40];
    __shared__ f16 Bf[160 * 40];
    const int tid = threadIdx.x;
    const int m0 = blockIdx.x * 64;
    const int sk = blockIdx.y;
    const int kbase = sk * KC;
    const int lane = tid & 63;
    const int wv = tid >> 6;
    const int col = lane & 15;
    const int kg = lane >> 4;

    f32x4 acc[10];
#pragma unroll
    for (int i = 0; i < 10; i++) acc[i] = (f32x4){0.f, 0.f, 0.f, 0.f};

    for (int ks = 0; ks < KC / 32; ks++) {
        const int kb = kbase + ks * 32;
        if (ks) __syncthreads();
#pragma unroll
        for (int j = 0; j < 2; j++) {
            int f = tid + j * 256;
            int m = f >> 3, kq = f & 7;
            float4 v = *(const float4*)(x + (size_t)(m0 + m) * Dm + kb + kq * 4);
            f16x4 h = {(f16)v.x, (f16)v.y, (f16)v.z, (f16)v.w};
            *(f16x4*)((char*)Af + m * 80 + kq * 8) = h;
        }
#pragma unroll
        for (int j = 0; j < 5; j++) {
            int f = tid + j * 256;
            int n = f >> 3, kq = f & 7;
            float4 v = *(const float4*)(w + (size_t)n * Dm + kb + kq * 4);
            f16x4 h = {(f16)v.x, (f16)v.y, (f16)v.z, (f16)v.w};
            *(f16x4*)((char*)Bf + n * 80 + kq * 8) = h;
        }
        __syncthreads();
        f16x8 a = *(const f16x8*)((char*)Af + (wv * 16 + col) * 80 + kg * 16);
#pragma unroll
        for (int nf = 0; nf < 10; nf++) {
            f16x8 b = *(const f16x8*)((char*)Bf + (nf * 16 + col) * 80 + kg * 16);
            acc[nf] = __builtin_amdgcn_mfma_f32_16x16x32_f16(a, b, acc[nf], 0, 0, 0);
        }
    }
    float* Pb = P + (size_t)sk * Mm * 160 + (size_t)m0 * 160;
#pragma unroll
    for (int nf = 0; nf < 10; nf++)
#pragma unroll
        for (int r = 0; r < 4; r++) {
            int row = wv * 16 + kg * 4 + r;
            Pb[(size_t)row * 160 + nf * 16 + col] = acc[nf][r];
        }
}

// ---------------- reduce split-K, pack delta_un (fp16) / Bm / Cm ------------
__global__ __launch_bounds__(256) void k_red1(const float* __restrict__ P,
                                              f16* __restrict__ dun,
                                              float* __restrict__ Bm,
                                              float* __restrict__ Cm) {
    int e = blockIdx.x * 256 + threadIdx.x;
    int m = e / 160, c = e % 160;
    float v = 0.f;
#pragma unroll
    for (int s = 0; s < SK; s++) v += P[(size_t)s * Mm * 160 + e];
    if (c < 128)      dun[(size_t)m * Rr + c] = (f16)v;
    else if (c < 144) Bm[(size_t)m * 16 + (c - 128)] = v;
    else              Cm[(size_t)m * 16 + (c - 144)] = v;
}

// ---------------- GEMM2: delta16 = softplus(dun . dtw^T + b) ----------------
__global__ __launch_bounds__(256) void k_gemm2(const f16* __restrict__ dun,
                                               const f16* __restrict__ dtw16,
                                               const float* __restrict__ bias,
                                               f16* __restrict__ delta) {
    __shared__ f16 Ad[64 * 128];
    __shared__ f16 Bd[128 * 128];
    const int tid = threadIdx.x;
    const int lane = tid & 63;
    const int wv = tid >> 6;
    const int m0 = blockIdx.x * 64;
    const int n0 = blockIdx.y * 128;
    const int col = lane & 15;
    const int kg = lane >> 4;
    const int wm = wv & 1, wn = wv >> 1;

    const uint4* gA = (const uint4*)(dun + (size_t)m0 * Rr);
#pragma unroll
    for (int j = 0; j < 4; j++) {
        int slot = tid + j * 256;
        uint4 v = gA[slot];
        int off = slot * 16;
        int row = slot >> 4;
        *(uint4*)((char*)Ad + (off ^ ((row & 7) << 4))) = v;
    }
    const uint4* gB = (const uint4*)(dtw16 + (size_t)n0 * Rr);
#pragma unroll
    for (int j = 0; j < 8; j++) {
        int slot = tid + j * 256;
        uint4 v = gB[slot];
        int off = slot * 16;
        int row = slot >> 4;
        *(uint4*)((char*)Bd + (off ^ ((row & 7) << 4))) = v;
    }
    __syncthreads();

    f32x4 acc[2][4];
#pragma unroll
    for (int i = 0; i < 2; i++)
#pragma unroll
        for (int j = 0; j < 4; j++) acc[i][j] = (f32x4){0.f, 0.f, 0.f, 0.f};

#pragma unroll
    for (int ks = 0; ks < 4; ks++) {
        f16x8 a[2], b[4];
#pragma unroll
        for (int mf = 0; mf < 2; mf++) {
            int row = wm * 32 + mf * 16 + col;
            int off = (row << 8) + ks * 64 + kg * 16;
            a[mf] = *(const f16x8*)((char*)Ad + (off ^ ((row & 7) << 4)));
        }
#pragma unroll
        for (int nf = 0; nf < 4; nf++) {
            int row = wn * 64 + nf * 16 + col;
            int off = (row << 8) + ks * 64 + kg * 16;
            b[nf] = *(const f16x8*)((char*)Bd + (off ^ ((row & 7) << 4)));
        }
#pragma unroll
        for (int mf = 0; mf < 2; mf++)
#pragma unroll
            for (int nf = 0; nf < 4; nf++)
                acc[mf][nf] = __builtin_amdgcn_mfma_f32_16x16x32_f16(a[mf], b[nf], acc[mf][nf], 0, 0, 0);
    }
#pragma unroll
    for (int mf = 0; mf < 2; mf++)
#pragma unroll
        for (int nf = 0; nf < 4; nf++) {
            int gd = n0 + wn * 64 + nf * 16 + col;
            float bv = bias[gd];
#pragma unroll
            for (int r = 0; r < 4; r++) {
                int gm = m0 + wm * 32 + mf * 16 + kg * 4 + r;
                float v = acc[mf][nf][r] + bv;
                float sp = (v > 15.f) ? v : log1pf(expf(v));
                delta[(size_t)gm * Dm + gd] = (f16)sp;
            }
        }
}

// ---------------- scan helpers ----------------------------------------------
#define UPD(q, bv)                                                   \
    s[q * 4 + 0] = fmaf(exp2f(dc * a2[q * 4 + 0]), s[q * 4 + 0], dx * bv.x); \
    s[q * 4 + 1] = fmaf(exp2f(dc * a2[q * 4 + 1]), s[q * 4 + 1], dx * bv.y); \
    s[q * 4 + 2] = fmaf(exp2f(dc * a2[q * 4 + 2]), s[q * 4 + 2], dx * bv.z); \
    s[q * 4 + 3] = fmaf(exp2f(dc * a2[q * 4 + 3]), s[q * 4 + 3], dx * bv.w);

#define DOT(q, cv)                                \
    ya = fmaf(s[q * 4 + 0], cv.x, ya);            \
    yb = fmaf(s[q * 4 + 1], cv.y, yb);            \
    yc = fmaf(s[q * 4 + 2], cv.z, yc);            \
    yd = fmaf(s[q * 4 + 3], cv.w, yd);

// Ap/Sl/S0 layout: [b][c][n][d] (fp16), coalesced per-n
// ---------------- scan phase 1: chunk summaries -----------------------------
__global__ __launch_bounds__(256, 4) void k_scan1(const f16* __restrict__ delta,
                                                  const float* __restrict__ x,
                                                  const float* __restrict__ Bm,
                                                  const float* __restrict__ a2g,
                                                  f16* __restrict__ Ap,
                                                  f16* __restrict__ Sl) {
    __shared__ float Bl[LC * 16];
    const int tid = threadIdx.x;
    const int d = blockIdx.x * 256 + tid;
    const int c = blockIdx.y;
    const int b = blockIdx.z;
    const int l0 = c * LC;

    if (tid < LC * 4)
        ((float4*)Bl)[tid] = ((const float4*)(Bm + (size_t)(b * Ls + l0) * 16))[tid];

    float a2[16];
#pragma unroll
    for (int n = 0; n < 16; n++) a2[n] = a2g[(size_t)n * Dm + d];

    float s[16];
#pragma unroll
    for (int n = 0; n < 16; n++) s[n] = 0.f;
    float dsum = 0.f;

    __syncthreads();

    const f16* dptr = delta + (size_t)(b * Ls + l0) * Dm + d;
    const float* xptr = x + (size_t)(b * Ls + l0) * Dm + d;
    const float4* Bl4 = (const float4*)Bl;

    float dcur[4], xcur[4];
#pragma unroll
    for (int j = 0; j < 4; j++) {
        dcur[j] = (float)dptr[(size_t)j * Dm];
        xcur[j] = xptr[(size_t)j * Dm];
    }

    for (int g = 0; g < LC / 4; g++) {
        float dnx[4], xnx[4];
        const int nb = (g + 1 < LC / 4) ? (g + 1) * 4 : g * 4;
#pragma unroll
        for (int j = 0; j < 4; j++) {
            dnx[j] = (float)dptr[(size_t)(nb + j) * Dm];
            xnx[j] = xptr[(size_t)(nb + j) * Dm];
        }
#pragma unroll
        for (int j = 0; j < 4; j++) {
            const int i = g * 4 + j;
            float dc = dcur[j], xc = xcur[j];
            float4 b0 = Bl4[i * 4 + 0], b1 = Bl4[i * 4 + 1];
            float4 b2 = Bl4[i * 4 + 2], b3 = Bl4[i * 4 + 3];
            float dx = dc * xc;
            dsum += dc;
            UPD(0, b0) UPD(1, b1) UPD(2, b2) UPD(3, b3)
        }
#pragma unroll
        for (int j = 0; j < 4; j++) { dcur[j] = dnx[j]; xcur[j] = xnx[j]; }
    }

    size_t ob = ((size_t)(b * NC + c) * 16) * Dm + d;
#pragma unroll
    for (int n = 0; n < 16; n++) {
        Ap[ob + (size_t)n * Dm] = (f16)exp2f(dsum * a2[n]);
        Sl[ob + (size_t)n * Dm] = (f16)s[n];
    }
}

// ---------------- scan phase 2: sequential chunk combine --------------------
__global__ __launch_bounds__(256) void k_scan2(const f16* __restrict__ Ap,
                                               const f16* __restrict__ Sl,
                                               f16* __restrict__ S0) {
    int e = blockIdx.x * 256 + threadIdx.x;   // < Bb*16*Dm
    int d = e & (Dm - 1);
    int n = (e >> 11) & 15;
    int b = e >> 15;
    size_t base = ((size_t)(b * NC) * 16 + n) * Dm + d;
    const size_t cs = (size_t)16 * Dm;
    float s = 0.f;
    for (int cg = 0; cg < NC / 8; cg++) {
        f16 apb[8], slb[8];
#pragma unroll
        for (int j = 0; j < 8; j++) {
            apb[j] = Ap[base + (size_t)(cg * 8 + j) * cs];
            slb[j] = Sl[base + (size_t)(cg * 8 + j) * cs];
        }
#pragma unroll
        for (int j = 0; j < 8; j++) {
            S0[base + (size_t)(cg * 8 + j) * cs] = (f16)s;
            s = fmaf((float)apb[j], s, (float)slb[j]);
        }
    }
}

// ---------------- scan phase 3: recompute with true init, emit y ------------
__global__ __launch_bounds__(256, 4) void k_scan3(const f16* __restrict__ delta,
                                                  const float* __restrict__ x,
                                                  const float* __restrict__ Bm,
                                                  const float* __restrict__ Cm,
                                                  const float* __restrict__ a2g,
                                                  const f16* __restrict__ S0,
                                                  const float* __restrict__ Dpar,
                                                  float* __restrict__ out) {
    __shared__ float Bl[LC * 16];
    __shared__ float Cl[LC * 16];
    const int tid = threadIdx.x;
    const int d = blockIdx.x * 256 + tid;
    const int c = blockIdx.y;
    const int b = blockIdx.z;
    const int l0 = c * LC;

    if (tid < LC * 4)
        ((float4*)Bl)[tid] = ((const float4*)(Bm + (size_t)(b * Ls + l0) * 16))[tid];
    else if (tid < LC * 8)
        ((float4*)Cl)[tid - LC * 4] = ((const float4*)(Cm + (size_t)(b * Ls + l0) * 16))[tid - LC * 4];

    float a2[16];
#pragma unroll
    for (int n = 0; n < 16; n++) a2[n] = a2g[(size_t)n * Dm + d];

    size_t ob = ((size_t)(b * NC + c) * 16) * Dm + d;
    float s[16];
#pragma unroll
    for (int n = 0; n < 16; n++) s[n] = (float)S0[ob + (size_t)n * Dm];

    float Dp = Dpar[d];

    __syncthreads();

    const f16* dptr = delta + (size_t)(b * Ls + l0) * Dm + d;
    const float* xptr = x + (size_t)(b * Ls + l0) * Dm + d;
    float* optr = out + (size_t)(b * Ls + l0) * Dm + d;
    const float4* Bl4 = (const float4*)Bl;
    const float4* Cl4 = (const float4*)Cl;

    float dcur[4], xcur[4];
#pragma unroll
    for (int j = 0; j < 4; j++) {
        dcur[j] = (float)dptr[(size_t)j * Dm];
        xcur[j] = xptr[(size_t)j * Dm];
    }

    for (int g = 0; g < LC / 4; g++) {
        float dnx[4], xnx[4];
        const int nb = (g + 1 < LC / 4) ? (g + 1) * 4 : g * 4;
#pragma unroll
        for (int j = 0; j < 4; j++) {
            dnx[j] = (float)dptr[(size_t)(nb + j) * Dm];
            xnx[j] = xptr[(size_t)(nb + j) * Dm];
        }
#pragma unroll
        for (int j = 0; j < 4; j++) {
            const int i = g * 4 + j;
            float dc = dcur[j], xc = xcur[j];
            float4 b0 = Bl4[i * 4 + 0], b1 = Bl4[i * 4 + 1];
            float4 b2 = Bl4[i * 4 + 2], b3 = Bl4[i * 4 + 3];
            float4 c0 = Cl4[i * 4 + 0], c1 = Cl4[i * 4 + 1];
            float4 c2 = Cl4[i * 4 + 2], c3 = Cl4[i * 4 + 3];
            float dx = dc * xc;
            UPD(0, b0) UPD(1, b1) UPD(2, b2) UPD(3, b3)
            float ya = 0.f, yb = 0.f, yc = 0.f, yd = 0.f;
            DOT(0, c0) DOT(1, c1) DOT(2, c2) DOT(3, c3)
            optr[(size_t)i * Dm] = fmaf(xc, Dp, (ya + yb) + (yc + yd));
        }
#pragma unroll
        for (int j = 0; j < 4; j++) { dcur[j] = dnx[j]; xcur[j] = xnx[j]; }
    }
}

// ---------------- host launcher ---------------------------------------------
extern "C" void kernel_launch(void* const* d_in, const int* in_sizes, int n_in,
                              void* d_out, int out_size, void* d_ws, size_t ws_size,
                              hipStream_t stream) {
    const float* x    = (const float*)d_in[0];
    const float* xw   = (const float*)d_in[1];
    const float* dtw  = (const float*)d_in[2];
    const float* dtb  = (const float*)d_in[3];
    const float* alog = (const float*)d_in[4];
    const float* dpar = (const float*)d_in[5];
    float* out = (float*)d_out;

    char* ws = (char*)d_ws;
    size_t off = 0;
    auto alloc = [&](size_t bytes) {
        char* p = ws + off;
        off += (bytes + 255) & ~(size_t)255;
        return p;
    };
    f16*   dun    = (f16*)  alloc((size_t)Mm * Rr * 2);             // 1 MB
    float* BmA    = (float*)alloc((size_t)Mm * 16 * 4);             // 256 KB
    float* CmA    = (float*)alloc((size_t)Mm * 16 * 4);             // 256 KB
    float* Pp     = (float*)alloc((size_t)SK * Mm * 160 * 4);       // 10.5 MB
    f16*   deltaA = (f16*)  alloc((size_t)Mm * Dm * 2);             // 16.8 MB
    f16*   ApA    = (f16*)  alloc((size_t)Bb * NC * 16 * Dm * 2);   // 8 MB
    f16*   SlA    = (f16*)  alloc((size_t)Bb * NC * 16 * Dm * 2);   // 8 MB
    f16*   S0A    = (f16*)  alloc((size_t)Bb * NC * 16 * Dm * 2);   // 8 MB
    f16*   dtw16  = (f16*)  alloc((size_t)Dm * Rr * 2);             // 512 KB
    float* a2A    = (float*)alloc((size_t)Ns * Dm * 4);             // 128 KB

    hipLaunchKernelGGL(k_prep, dim3((Dm * Rr) / 256), dim3(256), 0, stream,
                       dtw, alog, dtw16, a2A);
    hipLaunchKernelGGL(k_gemm1, dim3(Mm / 64, SK), dim3(256), 0, stream, x, xw, Pp);
    hipLaunchKernelGGL(k_red1, dim3((Mm * 160) / 256), dim3(256), 0, stream,
                       Pp, dun, BmA, CmA);
    hipLaunchKernelGGL(k_gemm2, dim3(Mm / 64, Dm / 128), dim3(256), 0, stream,
                       dun, dtw16, dtb, deltaA);
    hipLaunchKernelGGL(k_scan1, dim3(Dm / 256, NC, Bb), dim3(256), 0, stream,
                       deltaA, x, BmA, a2A, ApA, SlA);
    hipLaunchKernelGGL(k_scan2, dim3((Bb * 16 * Dm) / 256), dim3(256), 0, stream,
                       ApA, SlA, S0A);
    hipLaunchKernelGGL(k_scan3, dim3(Dm / 256, NC, Bb), dim3(256), 0, stream,
                       deltaA, x, BmA, CmA, a2A, S0A, dpar, out);
}

// Round 4
// 125.302 us; speedup vs baseline: 1.3809x; 1.3365x over previous
//
#include <hip/hip_runtime.h>
#include <math.h>

typedef _Float16 f16;
typedef _Float16 f16x8 __attribute__((ext_vector_type(8)));
typedef _Float16 f16x4 __attribute__((ext_vector_type(4)));
typedef float f32x4 __attribute__((ext_vector_type(4)));

#define LOG2E 1.44269504088896340736f

static constexpr int Bb = 2;      // batch
static constexpr int Ls = 2048;   // seqlen
static constexpr int Dm = 2048;   // d_inner
static constexpr int Ns = 16;     // d_state
static constexpr int Rr = 128;    // dt_rank
static constexpr int Mm = Bb * Ls;   // 4096 rows (b*l)
static constexpr int NC = 64;        // scan chunks
static constexpr int LC = Ls / NC;   // 32 steps per chunk
static constexpr int SK = 4;         // split-K for GEMM1
static constexpr int KC = Dm / SK;   // 512

// ---------------- prep: dt_proj_w -> fp16, A2[n][d], fast-path check --------
__global__ __launch_bounds__(256) void k_prep(const float* __restrict__ dtw,
                                              const float* __restrict__ alog,
                                              f16* __restrict__ dtw16,
                                              float* __restrict__ a2,
                                              int* __restrict__ flag) {
    int i = blockIdx.x * 256 + threadIdx.x;
    if (i < Dm * Rr) dtw16[i] = (f16)dtw[i];
    if (i < Dm * Ns) {
        int d = i >> 4, n = i & 15;
        float av = -expf(alog[i]);                 // A[d][n]
        a2[n * Dm + d] = av * LOG2E;
        // fast path valid iff A[d][n] == -(n+1) (S4D-real init)
        if (fabsf(av + (float)(n + 1)) > 2e-5f * (float)(n + 1))
            atomicOr(flag, 1);
    }
}

// ---------------- GEMM1: x_dbl partials, split-K ----------------------------
__global__ __launch_bounds__(256) void k_gemm1(const float* __restrict__ x,
                                               const float* __restrict__ w,
                                               float* __restrict__ P) {
    __shared__ f16 Af[64 * 40];
    __shared__ f16 Bf[160 * 40];
    const int tid = threadIdx.x;
    const int m0 = blockIdx.x * 64;
    const int sk = blockIdx.y;
    const int kbase = sk * KC;
    const int lane = tid & 63;
    const int wv = tid >> 6;
    const int col = lane & 15;
    const int kg = lane >> 4;

    f32x4 acc[10];
#pragma unroll
    for (int i = 0; i < 10; i++) acc[i] = (f32x4){0.f, 0.f, 0.f, 0.f};

    for (int ks = 0; ks < KC / 32; ks++) {
        const int kb = kbase + ks * 32;
        if (ks) __syncthreads();
#pragma unroll
        for (int j = 0; j < 2; j++) {
            int f = tid + j * 256;
            int m = f >> 3, kq = f & 7;
            float4 v = *(const float4*)(x + (size_t)(m0 + m) * Dm + kb + kq * 4);
            f16x4 h = {(f16)v.x, (f16)v.y, (f16)v.z, (f16)v.w};
            *(f16x4*)((char*)Af + m * 80 + kq * 8) = h;
        }
#pragma unroll
        for (int j = 0; j < 5; j++) {
            int f = tid + j * 256;
            int n = f >> 3, kq = f & 7;
            float4 v = *(const float4*)(w + (size_t)n * Dm + kb + kq * 4);
            f16x4 h = {(f16)v.x, (f16)v.y, (f16)v.z, (f16)v.w};
            *(f16x4*)((char*)Bf + n * 80 + kq * 8) = h;
        }
        __syncthreads();
        f16x8 a = *(const f16x8*)((char*)Af + (wv * 16 + col) * 80 + kg * 16);
#pragma unroll
        for (int nf = 0; nf < 10; nf++) {
            f16x8 b = *(const f16x8*)((char*)Bf + (nf * 16 + col) * 80 + kg * 16);
            acc[nf] = __builtin_amdgcn_mfma_f32_16x16x32_f16(a, b, acc[nf], 0, 0, 0);
        }
    }
    float* Pb = P + (size_t)sk * Mm * 160 + (size_t)m0 * 160;
#pragma unroll
    for (int nf = 0; nf < 10; nf++)
#pragma unroll
        for (int r = 0; r < 4; r++) {
            int row = wv * 16 + kg * 4 + r;
            Pb[(size_t)row * 160 + nf * 16 + col] = acc[nf][r];
        }
}

// ---------------- reduce split-K, pack delta_un (fp16) / Bm / Cm ------------
__global__ __launch_bounds__(256) void k_red1(const float* __restrict__ P,
                                              f16* __restrict__ dun,
                                              float* __restrict__ Bm,
                                              float* __restrict__ Cm) {
    int e = blockIdx.x * 256 + threadIdx.x;
    int m = e / 160, c = e % 160;
    float v = 0.f;
#pragma unroll
    for (int s = 0; s < SK; s++) v += P[(size_t)s * Mm * 160 + e];
    if (c < 128)      dun[(size_t)m * Rr + c] = (f16)v;
    else if (c < 144) Bm[(size_t)m * 16 + (c - 128)] = v;
    else              Cm[(size_t)m * 16 + (c - 144)] = v;
}

// ---------------- GEMM2: delta16 = softplus(dun . dtw^T + b) ----------------
__global__ __launch_bounds__(256) void k_gemm2(const f16* __restrict__ dun,
                                               const f16* __restrict__ dtw16,
                                               const float* __restrict__ bias,
                                               f16* __restrict__ delta) {
    __shared__ f16 Ad[64 * 128];
    __shared__ f16 Bd[128 * 128];
    const int tid = threadIdx.x;
    const int lane = tid & 63;
    const int wv = tid >> 6;
    const int m0 = blockIdx.x * 64;
    const int n0 = blockIdx.y * 128;
    const int col = lane & 15;
    const int kg = lane >> 4;
    const int wm = wv & 1, wn = wv >> 1;

    const uint4* gA = (const uint4*)(dun + (size_t)m0 * Rr);
#pragma unroll
    for (int j = 0; j < 4; j++) {
        int slot = tid + j * 256;
        uint4 v = gA[slot];
        int off = slot * 16;
        int row = slot >> 4;
        *(uint4*)((char*)Ad + (off ^ ((row & 7) << 4))) = v;
    }
    const uint4* gB = (const uint4*)(dtw16 + (size_t)n0 * Rr);
#pragma unroll
    for (int j = 0; j < 8; j++) {
        int slot = tid + j * 256;
        uint4 v = gB[slot];
        int off = slot * 16;
        int row = slot >> 4;
        *(uint4*)((char*)Bd + (off ^ ((row & 7) << 4))) = v;
    }
    __syncthreads();

    f32x4 acc[2][4];
#pragma unroll
    for (int i = 0; i < 2; i++)
#pragma unroll
        for (int j = 0; j < 4; j++) acc[i][j] = (f32x4){0.f, 0.f, 0.f, 0.f};

#pragma unroll
    for (int ks = 0; ks < 4; ks++) {
        f16x8 a[2], b[4];
#pragma unroll
        for (int mf = 0; mf < 2; mf++) {
            int row = wm * 32 + mf * 16 + col;
            int off = (row << 8) + ks * 64 + kg * 16;
            a[mf] = *(const f16x8*)((char*)Ad + (off ^ ((row & 7) << 4)));
        }
#pragma unroll
        for (int nf = 0; nf < 4; nf++) {
            int row = wn * 64 + nf * 16 + col;
            int off = (row << 8) + ks * 64 + kg * 16;
            b[nf] = *(const f16x8*)((char*)Bd + (off ^ ((row & 7) << 4)));
        }
#pragma unroll
        for (int mf = 0; mf < 2; mf++)
#pragma unroll
            for (int nf = 0; nf < 4; nf++)
                acc[mf][nf] = __builtin_amdgcn_mfma_f32_16x16x32_f16(a[mf], b[nf], acc[mf][nf], 0, 0, 0);
    }
#pragma unroll
    for (int mf = 0; mf < 2; mf++)
#pragma unroll
        for (int nf = 0; nf < 4; nf++) {
            int gd = n0 + wn * 64 + nf * 16 + col;
            float bv = bias[gd];
#pragma unroll
            for (int r = 0; r < 4; r++) {
                int gm = m0 + wm * 32 + mf * 16 + kg * 4 + r;
                float v = acc[mf][nf][r] + bv;
                float sp = (v > 15.f) ? v : log1pf(expf(v));
                delta[(size_t)gm * Dm + gd] = (f16)sp;
            }
        }
}

// block decode: dblk = bid&7, c = (bid>>3)&63, b = bid>>9
// Ap/Sl/S0 layout: [b][c][n][d] fp16

// ---------------- scan phase 1: LDS-staged chunk summaries ------------------
__global__ __launch_bounds__(256, 4) void k_scan1(const f16* __restrict__ delta,
                                                  const float* __restrict__ x,
                                                  const float* __restrict__ Bm,
                                                  const float* __restrict__ a2g,
                                                  const int* __restrict__ flag,
                                                  f16* __restrict__ Ap,
                                                  f16* __restrict__ Sl) {
    __shared__ f16 dl[LC * 256];      // 16 KB
    __shared__ f16 xl[LC * 256];      // 16 KB
    __shared__ float bcl[LC * 16];    // 2 KB (B rows)

    const int tid = threadIdx.x;
    const int bid = blockIdx.x;
    const int dblk = bid & 7;
    const int c = (bid >> 3) & (NC - 1);
    const int b = bid >> 9;
    const int d0 = dblk * 256;
    const int d = d0 + tid;
    const int row0 = b * Ls + c * LC;

    if (tid < LC * 4) {
        int l = tid >> 2, q = tid & 3;
        *(float4*)&bcl[l * 16 + q * 4] = *(const float4*)(Bm + (size_t)(row0 + l) * 16 + q * 4);
    }
    {
        const char* src = (const char*)(delta + (size_t)row0 * Dm + d0);
#pragma unroll
        for (int j = 0; j < 4; j++) {
            int slot = tid + j * 256;         // 1024 x 16B
            int l = slot >> 5, o = slot & 31;
            uint4 v = *(const uint4*)(src + (size_t)l * Dm * 2 + o * 16);
            *(uint4*)((char*)dl + slot * 16) = v;
        }
    }
    {
        const float* src = x + (size_t)row0 * Dm + d0;
#pragma unroll
        for (int j = 0; j < 8; j++) {
            int slot = tid + j * 256;         // 2048 x float4
            int l = slot >> 6, o = slot & 63;
            float4 v = *(const float4*)(src + (size_t)l * Dm + o * 4);
            f16x4 h = {(f16)v.x, (f16)v.y, (f16)v.z, (f16)v.w};
            *(f16x4*)((char*)xl + slot * 8) = h;
        }
    }
    const bool fastp = (*flag == 0);
    float s[16];
#pragma unroll
    for (int n = 0; n < 16; n++) s[n] = 0.f;
    float dsum = 0.f;
    float a2r[16];
    if (!fastp) {
#pragma unroll
        for (int n = 0; n < 16; n++) a2r[n] = a2g[(size_t)n * Dm + d];
    }
    __syncthreads();

    if (fastp) {
#pragma unroll 4
        for (int i = 0; i < LC; i++) {
            float dc = (float)dl[i * 256 + tid];
            float xc = (float)xl[i * 256 + tid];
            float dx = dc * xc;
            dsum += dc;
            float w1 = exp2f(dc * (-LOG2E));       // e^{-dc}
            float w2 = w1 * w1, w3 = w2 * w1, w4 = w2 * w2;
            float w8 = w4 * w4, w12 = w8 * w4;
            float4 b0 = *(const float4*)&bcl[i * 16 + 0];
            float4 b1 = *(const float4*)&bcl[i * 16 + 4];
            float4 b2 = *(const float4*)&bcl[i * 16 + 8];
            float4 b3 = *(const float4*)&bcl[i * 16 + 12];
            s[0] = fmaf(w1, s[0], dx * b0.x);  s[1] = fmaf(w2, s[1], dx * b0.y);
            s[2] = fmaf(w3, s[2], dx * b0.z);  s[3] = fmaf(w4, s[3], dx * b0.w);
            s[4] = fmaf(w4 * w1, s[4], dx * b1.x);  s[5] = fmaf(w4 * w2, s[5], dx * b1.y);
            s[6] = fmaf(w4 * w3, s[6], dx * b1.z);  s[7] = fmaf(w8, s[7], dx * b1.w);
            s[8] = fmaf(w8 * w1, s[8], dx * b2.x);  s[9] = fmaf(w8 * w2, s[9], dx * b2.y);
            s[10] = fmaf(w8 * w3, s[10], dx * b2.z); s[11] = fmaf(w12, s[11], dx * b2.w);
            s[12] = fmaf(w12 * w1, s[12], dx * b3.x); s[13] = fmaf(w12 * w2, s[13], dx * b3.y);
            s[14] = fmaf(w12 * w3, s[14], dx * b3.z); s[15] = fmaf(w12 * w4, s[15], dx * b3.w);
        }
    } else {
        for (int i = 0; i < LC; i++) {
            float dc = (float)dl[i * 256 + tid];
            float xc = (float)xl[i * 256 + tid];
            float dx = dc * xc;
            dsum += dc;
#pragma unroll
            for (int n = 0; n < 16; n++)
                s[n] = fmaf(exp2f(dc * a2r[n]), s[n], dx * bcl[i * 16 + n]);
        }
    }
    const size_t ob = ((size_t)(b * NC + c) * 16) * Dm + d;
    if (fastp) {
        float W1 = exp2f(dsum * (-LOG2E));
        float W2 = W1 * W1, W3 = W2 * W1, W4 = W2 * W2;
        float W8 = W4 * W4, W12 = W8 * W4;
        Ap[ob + 0 * Dm] = (f16)W1;          Ap[ob + 1 * Dm] = (f16)W2;
        Ap[ob + 2 * Dm] = (f16)W3;          Ap[ob + 3 * Dm] = (f16)W4;
        Ap[ob + 4 * Dm] = (f16)(W4 * W1);   Ap[ob + 5 * Dm] = (f16)(W4 * W2);
        Ap[ob + 6 * Dm] = (f16)(W4 * W3);   Ap[ob + 7 * Dm] = (f16)W8;
        Ap[ob + 8 * Dm] = (f16)(W8 * W1);   Ap[ob + 9 * Dm] = (f16)(W8 * W2);
        Ap[ob + 10 * Dm] = (f16)(W8 * W3);  Ap[ob + 11 * Dm] = (f16)W12;
        Ap[ob + 12 * Dm] = (f16)(W12 * W1); Ap[ob + 13 * Dm] = (f16)(W12 * W2);
        Ap[ob + 14 * Dm] = (f16)(W12 * W3); Ap[ob + 15 * Dm] = (f16)(W12 * W4);
    } else {
#pragma unroll
        for (int n = 0; n < 16; n++)
            Ap[ob + (size_t)n * Dm] = (f16)exp2f(dsum * a2r[n]);
    }
#pragma unroll
    for (int n = 0; n < 16; n++) Sl[ob + (size_t)n * Dm] = (f16)s[n];
}

// ---------------- scan phase 2: sequential chunk combine --------------------
__global__ __launch_bounds__(256) void k_scan2(const f16* __restrict__ Ap,
                                               const f16* __restrict__ Sl,
                                               f16* __restrict__ S0) {
    int e = blockIdx.x * 256 + threadIdx.x;   // < Bb*16*Dm
    int d = e & (Dm - 1);
    int n = (e >> 11) & 15;
    int b = e >> 15;
    size_t base = ((size_t)(b * NC) * 16 + n) * Dm + d;
    const size_t cs = (size_t)16 * Dm;
    float s = 0.f;
    for (int cg = 0; cg < NC / 8; cg++) {
        float apb[8], slb[8];
#pragma unroll
        for (int j = 0; j < 8; j++) {
            apb[j] = (float)Ap[base + (size_t)(cg * 8 + j) * cs];
            slb[j] = (float)Sl[base + (size_t)(cg * 8 + j) * cs];
        }
#pragma unroll
        for (int j = 0; j < 8; j++) {
            S0[base + (size_t)(cg * 8 + j) * cs] = (f16)s;
            s = fmaf(apb[j], s, slb[j]);
        }
    }
}

// ---------------- scan phase 3: LDS-staged rescan, emit y -------------------
__global__ __launch_bounds__(256, 4) void k_scan3(const f16* __restrict__ delta,
                                                  const float* __restrict__ x,
                                                  const float* __restrict__ Bm,
                                                  const float* __restrict__ Cm,
                                                  const float* __restrict__ a2g,
                                                  const int* __restrict__ flag,
                                                  const f16* __restrict__ S0,
                                                  const float* __restrict__ Dpar,
                                                  float* __restrict__ out) {
    __shared__ f16 dl[LC * 256];      // 16 KB
    __shared__ f16 xl[LC * 256];      // 16 KB
    __shared__ float bcl[LC * 32];    // 4 KB (B row | C row)

    const int tid = threadIdx.x;
    const int bid = blockIdx.x;
    const int dblk = bid & 7;
    const int c = (bid >> 3) & (NC - 1);
    const int b = bid >> 9;
    const int d0 = dblk * 256;
    const int d = d0 + tid;
    const int row0 = b * Ls + c * LC;

    if (tid < LC * 4) {
        int l = tid >> 2, q = tid & 3;
        *(float4*)&bcl[l * 32 + q * 4] = *(const float4*)(Bm + (size_t)(row0 + l) * 16 + q * 4);
    } else if (tid < LC * 8) {
        int t = tid - LC * 4;
        int l = t >> 2, q = t & 3;
        *(float4*)&bcl[l * 32 + 16 + q * 4] = *(const float4*)(Cm + (size_t)(row0 + l) * 16 + q * 4);
    }
    {
        const char* src = (const char*)(delta + (size_t)row0 * Dm + d0);
#pragma unroll
        for (int j = 0; j < 4; j++) {
            int slot = tid + j * 256;
            int l = slot >> 5, o = slot & 31;
            uint4 v = *(const uint4*)(src + (size_t)l * Dm * 2 + o * 16);
            *(uint4*)((char*)dl + slot * 16) = v;
        }
    }
    {
        const float* src = x + (size_t)row0 * Dm + d0;
#pragma unroll
        for (int j = 0; j < 8; j++) {
            int slot = tid + j * 256;
            int l = slot >> 6, o = slot & 63;
            float4 v = *(const float4*)(src + (size_t)l * Dm + o * 4);
            f16x4 h = {(f16)v.x, (f16)v.y, (f16)v.z, (f16)v.w};
            *(f16x4*)((char*)xl + slot * 8) = h;
        }
    }
    const bool fastp = (*flag == 0);
    const size_t ob = ((size_t)(b * NC + c) * 16) * Dm + d;
    float s[16];
#pragma unroll
    for (int n = 0; n < 16; n++) s[n] = (float)S0[ob + (size_t)n * Dm];
    float a2r[16];
    if (!fastp) {
#pragma unroll
        for (int n = 0; n < 16; n++) a2r[n] = a2g[(size_t)n * Dm + d];
    }
    const float Dp = Dpar[d];
    float* optr = out + (size_t)row0 * Dm + d;
    __syncthreads();

    if (fastp) {
#pragma unroll 4
        for (int i = 0; i < LC; i++) {
            float dc = (float)dl[i * 256 + tid];
            float xc = (float)xl[i * 256 + tid];
            float dx = dc * xc;
            float w1 = exp2f(dc * (-LOG2E));
            float w2 = w1 * w1, w3 = w2 * w1, w4 = w2 * w2;
            float w8 = w4 * w4, w12 = w8 * w4;
            float4 b0 = *(const float4*)&bcl[i * 32 + 0];
            float4 b1 = *(const float4*)&bcl[i * 32 + 4];
            float4 b2 = *(const float4*)&bcl[i * 32 + 8];
            float4 b3 = *(const float4*)&bcl[i * 32 + 12];
            float4 c0 = *(const float4*)&bcl[i * 32 + 16];
            float4 c1 = *(const float4*)&bcl[i * 32 + 20];
            float4 c2 = *(const float4*)&bcl[i * 32 + 24];
            float4 c3 = *(const float4*)&bcl[i * 32 + 28];
            s[0] = fmaf(w1, s[0], dx * b0.x);  s[1] = fmaf(w2, s[1], dx * b0.y);
            s[2] = fmaf(w3, s[2], dx * b0.z);  s[3] = fmaf(w4, s[3], dx * b0.w);
            s[4] = fmaf(w4 * w1, s[4], dx * b1.x);  s[5] = fmaf(w4 * w2, s[5], dx * b1.y);
            s[6] = fmaf(w4 * w3, s[6], dx * b1.z);  s[7] = fmaf(w8, s[7], dx * b1.w);
            s[8] = fmaf(w8 * w1, s[8], dx * b2.x);  s[9] = fmaf(w8 * w2, s[9], dx * b2.y);
            s[10] = fmaf(w8 * w3, s[10], dx * b2.z); s[11] = fmaf(w12, s[11], dx * b2.w);
            s[12] = fmaf(w12 * w1, s[12], dx * b3.x); s[13] = fmaf(w12 * w2, s[13], dx * b3.y);
            s[14] = fmaf(w12 * w3, s[14], dx * b3.z); s[15] = fmaf(w12 * w4, s[15], dx * b3.w);
            float y0 = s[0] * c0.x, y1 = s[1] * c0.y, y2 = s[2] * c0.z, y3 = s[3] * c0.w;
            y0 = fmaf(s[4], c1.x, y0); y1 = fmaf(s[5], c1.y, y1);
            y2 = fmaf(s[6], c1.z, y2); y3 = fmaf(s[7], c1.w, y3);
            y0 = fmaf(s[8], c2.x, y0); y1 = fmaf(s[9], c2.y, y1);
            y2 = fmaf(s[10], c2.z, y2); y3 = fmaf(s[11], c2.w, y3);
            y0 = fmaf(s[12], c3.x, y0); y1 = fmaf(s[13], c3.y, y1);
            y2 = fmaf(s[14], c3.z, y2); y3 = fmaf(s[15], c3.w, y3);
            optr[(size_t)i * Dm] = fmaf(xc, Dp, (y0 + y1) + (y2 + y3));
        }
    } else {
        for (int i = 0; i < LC; i++) {
            float dc = (float)dl[i * 256 + tid];
            float xc = (float)xl[i * 256 + tid];
            float dx = dc * xc;
            float yv = 0.f;
#pragma unroll
            for (int n = 0; n < 16; n++) {
                s[n] = fmaf(exp2f(dc * a2r[n]), s[n], dx * bcl[i * 32 + n]);
                yv = fmaf(s[n], bcl[i * 32 + 16 + n], yv);
            }
            optr[(size_t)i * Dm] = fmaf(xc, Dp, yv);
        }
    }
}

// ---------------- host launcher ---------------------------------------------
extern "C" void kernel_launch(void* const* d_in, const int* in_sizes, int n_in,
                              void* d_out, int out_size, void* d_ws, size_t ws_size,
                              hipStream_t stream) {
    const float* x    = (const float*)d_in[0];
    const float* xw   = (const float*)d_in[1];
    const float* dtw  = (const float*)d_in[2];
    const float* dtb  = (const float*)d_in[3];
    const float* alog = (const float*)d_in[4];
    const float* dpar = (const float*)d_in[5];
    float* out = (float*)d_out;

    char* ws = (char*)d_ws;
    size_t off = 0;
    auto alloc = [&](size_t bytes) {
        char* p = ws + off;
        off += (bytes + 255) & ~(size_t)255;
        return p;
    };
    f16*   dun    = (f16*)  alloc((size_t)Mm * Rr * 2);             // 1 MB
    float* BmA    = (float*)alloc((size_t)Mm * 16 * 4);             // 256 KB
    float* CmA    = (float*)alloc((size_t)Mm * 16 * 4);             // 256 KB
    float* Pp     = (float*)alloc((size_t)SK * Mm * 160 * 4);       // 10.5 MB
    f16*   deltaA = (f16*)  alloc((size_t)Mm * Dm * 2);             // 16.8 MB
    f16*   ApA    = (f16*)  alloc((size_t)Bb * NC * 16 * Dm * 2);   // 8 MB
    f16*   SlA    = (f16*)  alloc((size_t)Bb * NC * 16 * Dm * 2);   // 8 MB
    f16*   S0A    = (f16*)  alloc((size_t)Bb * NC * 16 * Dm * 2);   // 8 MB
    f16*   dtw16  = (f16*)  alloc((size_t)Dm * Rr * 2);             // 512 KB
    float* a2A    = (float*)alloc((size_t)Ns * Dm * 4);             // 128 KB
    int*   flagA  = (int*)  alloc(256);

    hipMemsetAsync(flagA, 0, 4, stream);
    hipLaunchKernelGGL(k_prep, dim3((Dm * Rr) / 256), dim3(256), 0, stream,
                       dtw, alog, dtw16, a2A, flagA);
    hipLaunchKernelGGL(k_gemm1, dim3(Mm / 64, SK), dim3(256), 0, stream, x, xw, Pp);
    hipLaunchKernelGGL(k_red1, dim3((Mm * 160) / 256), dim3(256), 0, stream,
                       Pp, dun, BmA, CmA);
    hipLaunchKernelGGL(k_gemm2, dim3(Mm / 64, Dm / 128), dim3(256), 0, stream,
                       dun, dtw16, dtb, deltaA);
    hipLaunchKernelGGL(k_scan1, dim3(Bb * 8 * NC), dim3(256), 0, stream,
                       deltaA, x, BmA, a2A, flagA, ApA, SlA);
    hipLaunchKernelGGL(k_scan2, dim3((Bb * 16 * Dm) / 256), dim3(256), 0, stream,
                       ApA, SlA, S0A);
    hipLaunchKernelGGL(k_scan3, dim3(Bb * 8 * NC), dim3(256), 0, stream,
                       deltaA, x, BmA, CmA, a2A, flagA, S0A, dpar, out);
}

// Round 5
// 124.032 us; speedup vs baseline: 1.3951x; 1.0102x over previous
//
#include <hip/hip_runtime.h>
#include <math.h>

typedef _Float16 f16;
typedef _Float16 f16x8 __attribute__((ext_vector_type(8)));
typedef _Float16 f16x4 __attribute__((ext_vector_type(4)));
typedef float f32x4 __attribute__((ext_vector_type(4)));

#define LOG2E 1.44269504088896340736f

static constexpr int Bb = 2;      // batch
static constexpr int Ls = 2048;   // seqlen
static constexpr int Dm = 2048;   // d_inner
static constexpr int Ns = 16;     // d_state
static constexpr int Rr = 128;    // dt_rank
static constexpr int Mm = Bb * Ls;   // 4096 rows (b*l)
static constexpr int NC = 64;        // scan chunks
static constexpr int LC = Ls / NC;   // 32 steps per chunk
static constexpr int SK = 4;         // split-K for GEMM1
static constexpr int KC = Dm / SK;   // 512

// ---------------- prep: dt_proj_w -> fp16, A2[n][d] -------------------------
__global__ __launch_bounds__(256) void k_prep(const float* __restrict__ dtw,
                                              const float* __restrict__ alog,
                                              f16* __restrict__ dtw16,
                                              float* __restrict__ a2) {
    int i = blockIdx.x * 256 + threadIdx.x;
    if (i < Dm * Rr) dtw16[i] = (f16)dtw[i];
    if (i < Dm * Ns) {
        int d = i >> 4, n = i & 15;
        a2[n * Dm + d] = -expf(alog[i]) * LOG2E;
    }
}

// per-thread fast-path check: a2r[n] == -(n+1)*LOG2E  (S4D-real init)
__device__ __forceinline__ bool fast_ok(const float* a2r) {
    bool ok = true;
#pragma unroll
    for (int n = 0; n < 16; n++)
        ok = ok && (fabsf(a2r[n] + (float)(n + 1) * LOG2E) <= 3e-5f * (float)(n + 1));
    return ok;
}

// ---------------- GEMM1: x_dbl partials, split-K ----------------------------
__global__ __launch_bounds__(256) void k_gemm1(const float* __restrict__ x,
                                               const float* __restrict__ w,
                                               float* __restrict__ P) {
    __shared__ f16 Af[64 * 40];
    __shared__ f16 Bf[160 * 40];
    const int tid = threadIdx.x;
    const int m0 = blockIdx.x * 64;
    const int sk = blockIdx.y;
    const int kbase = sk * KC;
    const int lane = tid & 63;
    const int wv = tid >> 6;
    const int col = lane & 15;
    const int kg = lane >> 4;

    f32x4 acc[10];
#pragma unroll
    for (int i = 0; i < 10; i++) acc[i] = (f32x4){0.f, 0.f, 0.f, 0.f};

    for (int ks = 0; ks < KC / 32; ks++) {
        const int kb = kbase + ks * 32;
        if (ks) __syncthreads();
#pragma unroll
        for (int j = 0; j < 2; j++) {
            int f = tid + j * 256;
            int m = f >> 3, kq = f & 7;
            float4 v = *(const float4*)(x + (size_t)(m0 + m) * Dm + kb + kq * 4);
            f16x4 h = {(f16)v.x, (f16)v.y, (f16)v.z, (f16)v.w};
            *(f16x4*)((char*)Af + m * 80 + kq * 8) = h;
        }
#pragma unroll
        for (int j = 0; j < 5; j++) {
            int f = tid + j * 256;
            int n = f >> 3, kq = f & 7;
            float4 v = *(const float4*)(w + (size_t)n * Dm + kb + kq * 4);
            f16x4 h = {(f16)v.x, (f16)v.y, (f16)v.z, (f16)v.w};
            *(f16x4*)((char*)Bf + n * 80 + kq * 8) = h;
        }
        __syncthreads();
        f16x8 a = *(const f16x8*)((char*)Af + (wv * 16 + col) * 80 + kg * 16);
#pragma unroll
        for (int nf = 0; nf < 10; nf++) {
            f16x8 b = *(const f16x8*)((char*)Bf + (nf * 16 + col) * 80 + kg * 16);
            acc[nf] = __builtin_amdgcn_mfma_f32_16x16x32_f16(a, b, acc[nf], 0, 0, 0);
        }
    }
    float* Pb = P + (size_t)sk * Mm * 160 + (size_t)m0 * 160;
#pragma unroll
    for (int nf = 0; nf < 10; nf++)
#pragma unroll
        for (int r = 0; r < 4; r++) {
            int row = wv * 16 + kg * 4 + r;
            Pb[(size_t)row * 160 + nf * 16 + col] = acc[nf][r];
        }
}

// ---------------- reduce split-K, pack delta_un (fp16) / Bm / Cm ------------
__global__ __launch_bounds__(256) void k_red1(const float* __restrict__ P,
                                              f16* __restrict__ dun,
                                              float* __restrict__ Bm,
                                              float* __restrict__ Cm) {
    int e = blockIdx.x * 256 + threadIdx.x;
    int m = e / 160, c = e % 160;
    float v = 0.f;
#pragma unroll
    for (int s = 0; s < SK; s++) v += P[(size_t)s * Mm * 160 + e];
    if (c < 128)      dun[(size_t)m * Rr + c] = (f16)v;
    else if (c < 144) Bm[(size_t)m * 16 + (c - 128)] = v;
    else              Cm[(size_t)m * 16 + (c - 144)] = v;
}

// ---------------- GEMM2: delta16 = softplus(dun . dtw^T + b) ----------------
__global__ __launch_bounds__(256) void k_gemm2(const f16* __restrict__ dun,
                                               const f16* __restrict__ dtw16,
                                               const float* __restrict__ bias,
                                               f16* __restrict__ delta) {
    __shared__ f16 Ad[64 * 128];
    __shared__ f16 Bd[128 * 128];
    const int tid = threadIdx.x;
    const int lane = tid & 63;
    const int wv = tid >> 6;
    const int m0 = blockIdx.x * 64;
    const int n0 = blockIdx.y * 128;
    const int col = lane & 15;
    const int kg = lane >> 4;
    const int wm = wv & 1, wn = wv >> 1;

    const uint4* gA = (const uint4*)(dun + (size_t)m0 * Rr);
#pragma unroll
    for (int j = 0; j < 4; j++) {
        int slot = tid + j * 256;
        uint4 v = gA[slot];
        int off = slot * 16;
        int row = slot >> 4;
        *(uint4*)((char*)Ad + (off ^ ((row & 7) << 4))) = v;
    }
    const uint4* gB = (const uint4*)(dtw16 + (size_t)n0 * Rr);
#pragma unroll
    for (int j = 0; j < 8; j++) {
        int slot = tid + j * 256;
        uint4 v = gB[slot];
        int off = slot * 16;
        int row = slot >> 4;
        *(uint4*)((char*)Bd + (off ^ ((row & 7) << 4))) = v;
    }
    __syncthreads();

    f32x4 acc[2][4];
#pragma unroll
    for (int i = 0; i < 2; i++)
#pragma unroll
        for (int j = 0; j < 4; j++) acc[i][j] = (f32x4){0.f, 0.f, 0.f, 0.f};

#pragma unroll
    for (int ks = 0; ks < 4; ks++) {
        f16x8 a[2], b[4];
#pragma unroll
        for (int mf = 0; mf < 2; mf++) {
            int row = wm * 32 + mf * 16 + col;
            int off = (row << 8) + ks * 64 + kg * 16;
            a[mf] = *(const f16x8*)((char*)Ad + (off ^ ((row & 7) << 4)));
        }
#pragma unroll
        for (int nf = 0; nf < 4; nf++) {
            int row = wn * 64 + nf * 16 + col;
            int off = (row << 8) + ks * 64 + kg * 16;
            b[nf] = *(const f16x8*)((char*)Bd + (off ^ ((row & 7) << 4)));
        }
#pragma unroll
        for (int mf = 0; mf < 2; mf++)
#pragma unroll
            for (int nf = 0; nf < 4; nf++)
                acc[mf][nf] = __builtin_amdgcn_mfma_f32_16x16x32_f16(a[mf], b[nf], acc[mf][nf], 0, 0, 0);
    }
#pragma unroll
    for (int mf = 0; mf < 2; mf++)
#pragma unroll
        for (int nf = 0; nf < 4; nf++) {
            int gd = n0 + wn * 64 + nf * 16 + col;
            float bv = bias[gd];
#pragma unroll
            for (int r = 0; r < 4; r++) {
                int gm = m0 + wm * 32 + mf * 16 + kg * 4 + r;
                float v = acc[mf][nf][r] + bv;
                float sp = (v > 15.f) ? v : log1pf(expf(v));
                delta[(size_t)gm * Dm + gd] = (f16)sp;
            }
        }
}

// block decode: dblk = bid&7, c = (bid>>3)&63, b = bid>>9
// Ap/Sl/S0 layout: [b][c][n][d] fp16

// ---------------- scan phase 1: LDS-staged chunk summaries ------------------
__global__ __launch_bounds__(256, 4) void k_scan1(const f16* __restrict__ delta,
                                                  const float* __restrict__ x,
                                                  const float* __restrict__ Bm,
                                                  const float* __restrict__ a2g,
                                                  f16* __restrict__ Ap,
                                                  f16* __restrict__ Sl) {
    __shared__ f16 dl[LC * 256];      // 16 KB
    __shared__ f16 xl[LC * 256];      // 16 KB
    __shared__ float bcl[LC * 16];    // 2 KB (B rows)

    const int tid = threadIdx.x;
    const int bid = blockIdx.x;
    const int dblk = bid & 7;
    const int c = (bid >> 3) & (NC - 1);
    const int b = bid >> 9;
    const int d0 = dblk * 256;
    const int d = d0 + tid;
    const int row0 = b * Ls + c * LC;

    if (tid < LC * 4) {
        int l = tid >> 2, q = tid & 3;
        *(float4*)&bcl[l * 16 + q * 4] = *(const float4*)(Bm + (size_t)(row0 + l) * 16 + q * 4);
    }
    {
        const char* src = (const char*)(delta + (size_t)row0 * Dm + d0);
#pragma unroll
        for (int j = 0; j < 4; j++) {
            int slot = tid + j * 256;         // 1024 x 16B
            int l = slot >> 5, o = slot & 31;
            uint4 v = *(const uint4*)(src + (size_t)l * Dm * 2 + o * 16);
            *(uint4*)((char*)dl + slot * 16) = v;
        }
    }
    {
        const float* src = x + (size_t)row0 * Dm + d0;
#pragma unroll
        for (int j = 0; j < 8; j++) {
            int slot = tid + j * 256;         // 2048 x float4
            int l = slot >> 6, o = slot & 63;
            float4 v = *(const float4*)(src + (size_t)l * Dm + o * 4);
            f16x4 h = {(f16)v.x, (f16)v.y, (f16)v.z, (f16)v.w};
            *(f16x4*)((char*)xl + slot * 8) = h;
        }
    }
    float a2r[16];
#pragma unroll
    for (int n = 0; n < 16; n++) a2r[n] = a2g[(size_t)n * Dm + d];
    const bool fastp = fast_ok(a2r);

    float s[16];
#pragma unroll
    for (int n = 0; n < 16; n++) s[n] = 0.f;
    float dsum = 0.f;
    __syncthreads();

    if (fastp) {
#pragma unroll 4
        for (int i = 0; i < LC; i++) {
            float dc = (float)dl[i * 256 + tid];
            float xc = (float)xl[i * 256 + tid];
            float dx = dc * xc;
            dsum += dc;
            float w1 = exp2f(dc * (-LOG2E));       // e^{-dc}
            float w2 = w1 * w1, w3 = w2 * w1, w4 = w2 * w2;
            float w8 = w4 * w4, w12 = w8 * w4;
            float4 b0 = *(const float4*)&bcl[i * 16 + 0];
            float4 b1 = *(const float4*)&bcl[i * 16 + 4];
            float4 b2 = *(const float4*)&bcl[i * 16 + 8];
            float4 b3 = *(const float4*)&bcl[i * 16 + 12];
            s[0] = fmaf(w1, s[0], dx * b0.x);  s[1] = fmaf(w2, s[1], dx * b0.y);
            s[2] = fmaf(w3, s[2], dx * b0.z);  s[3] = fmaf(w4, s[3], dx * b0.w);
            s[4] = fmaf(w4 * w1, s[4], dx * b1.x);  s[5] = fmaf(w4 * w2, s[5], dx * b1.y);
            s[6] = fmaf(w4 * w3, s[6], dx * b1.z);  s[7] = fmaf(w8, s[7], dx * b1.w);
            s[8] = fmaf(w8 * w1, s[8], dx * b2.x);  s[9] = fmaf(w8 * w2, s[9], dx * b2.y);
            s[10] = fmaf(w8 * w3, s[10], dx * b2.z); s[11] = fmaf(w12, s[11], dx * b2.w);
            s[12] = fmaf(w12 * w1, s[12], dx * b3.x); s[13] = fmaf(w12 * w2, s[13], dx * b3.y);
            s[14] = fmaf(w12 * w3, s[14], dx * b3.z); s[15] = fmaf(w12 * w4, s[15], dx * b3.w);
        }
    } else {
        for (int i = 0; i < LC; i++) {
            float dc = (float)dl[i * 256 + tid];
            float xc = (float)xl[i * 256 + tid];
            float dx = dc * xc;
            dsum += dc;
#pragma unroll
            for (int n = 0; n < 16; n++)
                s[n] = fmaf(exp2f(dc * a2r[n]), s[n], dx * bcl[i * 16 + n]);
        }
    }
    const size_t ob = ((size_t)(b * NC + c) * 16) * Dm + d;
    if (fastp) {
        float W1 = exp2f(dsum * (-LOG2E));
        float W2 = W1 * W1, W3 = W2 * W1, W4 = W2 * W2;
        float W8 = W4 * W4, W12 = W8 * W4;
        Ap[ob + 0 * Dm] = (f16)W1;          Ap[ob + 1 * Dm] = (f16)W2;
        Ap[ob + 2 * Dm] = (f16)W3;          Ap[ob + 3 * Dm] = (f16)W4;
        Ap[ob + 4 * Dm] = (f16)(W4 * W1);   Ap[ob + 5 * Dm] = (f16)(W4 * W2);
        Ap[ob + 6 * Dm] = (f16)(W4 * W3);   Ap[ob + 7 * Dm] = (f16)W8;
        Ap[ob + 8 * Dm] = (f16)(W8 * W1);   Ap[ob + 9 * Dm] = (f16)(W8 * W2);
        Ap[ob + 10 * Dm] = (f16)(W8 * W3);  Ap[ob + 11 * Dm] = (f16)W12;
        Ap[ob + 12 * Dm] = (f16)(W12 * W1); Ap[ob + 13 * Dm] = (f16)(W12 * W2);
        Ap[ob + 14 * Dm] = (f16)(W12 * W3); Ap[ob + 15 * Dm] = (f16)(W12 * W4);
    } else {
#pragma unroll
        for (int n = 0; n < 16; n++)
            Ap[ob + (size_t)n * Dm] = (f16)exp2f(dsum * a2r[n]);
    }
#pragma unroll
    for (int n = 0; n < 16; n++) Sl[ob + (size_t)n * Dm] = (f16)s[n];
}

// ---------------- scan phase 2: sequential chunk combine --------------------
__global__ __launch_bounds__(256) void k_scan2(const f16* __restrict__ Ap,
                                               const f16* __restrict__ Sl,
                                               f16* __restrict__ S0) {
    int e = blockIdx.x * 256 + threadIdx.x;   // < Bb*16*Dm
    int d = e & (Dm - 1);
    int n = (e >> 11) & 15;
    int b = e >> 15;
    size_t base = ((size_t)(b * NC) * 16 + n) * Dm + d;
    const size_t cs = (size_t)16 * Dm;
    float s = 0.f;
    for (int cg = 0; cg < NC / 8; cg++) {
        float apb[8], slb[8];
#pragma unroll
        for (int j = 0; j < 8; j++) {
            apb[j] = (float)Ap[base + (size_t)(cg * 8 + j) * cs];
            slb[j] = (float)Sl[base + (size_t)(cg * 8 + j) * cs];
        }
#pragma unroll
        for (int j = 0; j < 8; j++) {
            S0[base + (size_t)(cg * 8 + j) * cs] = (f16)s;
            s = fmaf(apb[j], s, slb[j]);
        }
    }
}

// ---------------- scan phase 3: LDS-staged rescan, emit y -------------------
__global__ __launch_bounds__(256, 4) void k_scan3(const f16* __restrict__ delta,
                                                  const float* __restrict__ x,
                                                  const float* __restrict__ Bm,
                                                  const float* __restrict__ Cm,
                                                  const float* __restrict__ a2g,
                                                  const f16* __restrict__ S0,
                                                  const float* __restrict__ Dpar,
                                                  float* __restrict__ out) {
    __shared__ f16 dl[LC * 256];      // 16 KB
    __shared__ f16 xl[LC * 256];      // 16 KB
    __shared__ float bcl[LC * 32];    // 4 KB (B row | C row)

    const int tid = threadIdx.x;
    const int bid = blockIdx.x;
    const int dblk = bid & 7;
    const int c = (bid >> 3) & (NC - 1);
    const int b = bid >> 9;
    const int d0 = dblk * 256;
    const int d = d0 + tid;
    const int row0 = b * Ls + c * LC;

    if (tid < LC * 4) {
        int l = tid >> 2, q = tid & 3;
        *(float4*)&bcl[l * 32 + q * 4] = *(const float4*)(Bm + (size_t)(row0 + l) * 16 + q * 4);
    } else if (tid < LC * 8) {
        int t = tid - LC * 4;
        int l = t >> 2, q = t & 3;
        *(float4*)&bcl[l * 32 + 16 + q * 4] = *(const float4*)(Cm + (size_t)(row0 + l) * 16 + q * 4);
    }
    {
        const char* src = (const char*)(delta + (size_t)row0 * Dm + d0);
#pragma unroll
        for (int j = 0; j < 4; j++) {
            int slot = tid + j * 256;
            int l = slot >> 5, o = slot & 31;
            uint4 v = *(const uint4*)(src + (size_t)l * Dm * 2 + o * 16);
            *(uint4*)((char*)dl + slot * 16) = v;
        }
    }
    {
        const float* src = x + (size_t)row0 * Dm + d0;
#pragma unroll
        for (int j = 0; j < 8; j++) {
            int slot = tid + j * 256;
            int l = slot >> 6, o = slot & 63;
            float4 v = *(const float4*)(src + (size_t)l * Dm + o * 4);
            f16x4 h = {(f16)v.x, (f16)v.y, (f16)v.z, (f16)v.w};
            *(f16x4*)((char*)xl + slot * 8) = h;
        }
    }
    float a2r[16];
#pragma unroll
    for (int n = 0; n < 16; n++) a2r[n] = a2g[(size_t)n * Dm + d];
    const bool fastp = fast_ok(a2r);

    const size_t ob = ((size_t)(b * NC + c) * 16) * Dm + d;
    float s[16];
#pragma unroll
    for (int n = 0; n < 16; n++) s[n] = (float)S0[ob + (size_t)n * Dm];
    const float Dp = Dpar[d];
    float* optr = out + (size_t)row0 * Dm + d;
    __syncthreads();

    if (fastp) {
#pragma unroll 4
        for (int i = 0; i < LC; i++) {
            float dc = (float)dl[i * 256 + tid];
            float xc = (float)xl[i * 256 + tid];
            float dx = dc * xc;
            float w1 = exp2f(dc * (-LOG2E));
            float w2 = w1 * w1, w3 = w2 * w1, w4 = w2 * w2;
            float w8 = w4 * w4, w12 = w8 * w4;
            float4 b0 = *(const float4*)&bcl[i * 32 + 0];
            float4 b1 = *(const float4*)&bcl[i * 32 + 4];
            float4 b2 = *(const float4*)&bcl[i * 32 + 8];
            float4 b3 = *(const float4*)&bcl[i * 32 + 12];
            float4 c0 = *(const float4*)&bcl[i * 32 + 16];
            float4 c1 = *(const float4*)&bcl[i * 32 + 20];
            float4 c2 = *(const float4*)&bcl[i * 32 + 24];
            float4 c3 = *(const float4*)&bcl[i * 32 + 28];
            s[0] = fmaf(w1, s[0], dx * b0.x);  s[1] = fmaf(w2, s[1], dx * b0.y);
            s[2] = fmaf(w3, s[2], dx * b0.z);  s[3] = fmaf(w4, s[3], dx * b0.w);
            s[4] = fmaf(w4 * w1, s[4], dx * b1.x);  s[5] = fmaf(w4 * w2, s[5], dx * b1.y);
            s[6] = fmaf(w4 * w3, s[6], dx * b1.z);  s[7] = fmaf(w8, s[7], dx * b1.w);
            s[8] = fmaf(w8 * w1, s[8], dx * b2.x);  s[9] = fmaf(w8 * w2, s[9], dx * b2.y);
            s[10] = fmaf(w8 * w3, s[10], dx * b2.z); s[11] = fmaf(w12, s[11], dx * b2.w);
            s[12] = fmaf(w12 * w1, s[12], dx * b3.x); s[13] = fmaf(w12 * w2, s[13], dx * b3.y);
            s[14] = fmaf(w12 * w3, s[14], dx * b3.z); s[15] = fmaf(w12 * w4, s[15], dx * b3.w);
            float y0 = s[0] * c0.x, y1 = s[1] * c0.y, y2 = s[2] * c0.z, y3 = s[3] * c0.w;
            y0 = fmaf(s[4], c1.x, y0); y1 = fmaf(s[5], c1.y, y1);
            y2 = fmaf(s[6], c1.z, y2); y3 = fmaf(s[7], c1.w, y3);
            y0 = fmaf(s[8], c2.x, y0); y1 = fmaf(s[9], c2.y, y1);
            y2 = fmaf(s[10], c2.z, y2); y3 = fmaf(s[11], c2.w, y3);
            y0 = fmaf(s[12], c3.x, y0); y1 = fmaf(s[13], c3.y, y1);
            y2 = fmaf(s[14], c3.z, y2); y3 = fmaf(s[15], c3.w, y3);
            optr[(size_t)i * Dm] = fmaf(xc, Dp, (y0 + y1) + (y2 + y3));
        }
    } else {
        for (int i = 0; i < LC; i++) {
            float dc = (float)dl[i * 256 + tid];
            float xc = (float)xl[i * 256 + tid];
            float dx = dc * xc;
            float yv = 0.f;
#pragma unroll
            for (int n = 0; n < 16; n++) {
                s[n] = fmaf(exp2f(dc * a2r[n]), s[n], dx * bcl[i * 32 + n]);
                yv = fmaf(s[n], bcl[i * 32 + 16 + n], yv);
            }
            optr[(size_t)i * Dm] = fmaf(xc, Dp, yv);
        }
    }
}

// ---------------- host launcher ---------------------------------------------
extern "C" void kernel_launch(void* const* d_in, const int* in_sizes, int n_in,
                              void* d_out, int out_size, void* d_ws, size_t ws_size,
                              hipStream_t stream) {
    const float* x    = (const float*)d_in[0];
    const float* xw   = (const float*)d_in[1];
    const float* dtw  = (const float*)d_in[2];
    const float* dtb  = (const float*)d_in[3];
    const float* alog = (const float*)d_in[4];
    const float* dpar = (const float*)d_in[5];
    float* out = (float*)d_out;

    char* ws = (char*)d_ws;
    size_t off = 0;
    auto alloc = [&](size_t bytes) {
        char* p = ws + off;
        off += (bytes + 255) & ~(size_t)255;
        return p;
    };
    f16*   dun    = (f16*)  alloc((size_t)Mm * Rr * 2);             // 1 MB
    float* BmA    = (float*)alloc((size_t)Mm * 16 * 4);             // 256 KB
    float* CmA    = (float*)alloc((size_t)Mm * 16 * 4);             // 256 KB
    float* Pp     = (float*)alloc((size_t)SK * Mm * 160 * 4);       // 10.5 MB
    f16*   deltaA = (f16*)  alloc((size_t)Mm * Dm * 2);             // 16.8 MB
    f16*   ApA    = (f16*)  alloc((size_t)Bb * NC * 16 * Dm * 2);   // 8 MB
    f16*   SlA    = (f16*)  alloc((size_t)Bb * NC * 16 * Dm * 2);   // 8 MB
    f16*   S0A    = (f16*)  alloc((size_t)Bb * NC * 16 * Dm * 2);   // 8 MB
    f16*   dtw16  = (f16*)  alloc((size_t)Dm * Rr * 2);             // 512 KB
    float* a2A    = (float*)alloc((size_t)Ns * Dm * 4);             // 128 KB

    hipLaunchKernelGGL(k_prep, dim3((Dm * Rr) / 256), dim3(256), 0, stream,
                       dtw, alog, dtw16, a2A);
    hipLaunchKernelGGL(k_gemm1, dim3(Mm / 64, SK), dim3(256), 0, stream, x, xw, Pp);
    hipLaunchKernelGGL(k_red1, dim3((Mm * 160) / 256), dim3(256), 0, stream,
                       Pp, dun, BmA, CmA);
    hipLaunchKernelGGL(k_gemm2, dim3(Mm / 64, Dm / 128), dim3(256), 0, stream,
                       dun, dtw16, dtb, deltaA);
    hipLaunchKernelGGL(k_scan1, dim3(Bb * 8 * NC), dim3(256), 0, stream,
                       deltaA, x, BmA, a2A, ApA, SlA);
    hipLaunchKernelGGL(k_scan2, dim3((Bb * 16 * Dm) / 256), dim3(256), 0, stream,
                       ApA, SlA, S0A);
    hipLaunchKernelGGL(k_scan3, dim3(Bb * 8 * NC), dim3(256), 0, stream,
                       deltaA, x, BmA, CmA, a2A, S0A, dpar, out);
}

// Round 6
// 116.839 us; speedup vs baseline: 1.4810x; 1.0616x over previous
//
#include <hip/hip_runtime.h>
#include <math.h>

typedef _Float16 f16;
typedef _Float16 f16x8 __attribute__((ext_vector_type(8)));
typedef _Float16 f16x4 __attribute__((ext_vector_type(4)));
typedef float f32x4 __attribute__((ext_vector_type(4)));

#define LOG2E 1.44269504088896340736f

static constexpr int Bb = 2;      // batch
static constexpr int Ls = 2048;   // seqlen
static constexpr int Dm = 2048;   // d_inner
static constexpr int Ns = 16;     // d_state
static constexpr int Rr = 128;    // dt_rank
static constexpr int Mm = Bb * Ls;   // 4096 rows (b*l)
static constexpr int NC = 64;        // scan chunks
static constexpr int LC = Ls / NC;   // 32 steps per chunk
static constexpr int SK = 8;         // split-K for GEMM1 (512 blocks = 2/CU)
static constexpr int KC = Dm / SK;   // 256

// ---------------- prep: dt_proj_w -> fp16, A2[n][d] -------------------------
__global__ __launch_bounds__(256) void k_prep(const float* __restrict__ dtw,
                                              const float* __restrict__ alog,
                                              f16* __restrict__ dtw16,
                                              float* __restrict__ a2) {
    int i = blockIdx.x * 256 + threadIdx.x;
    if (i < Dm * Rr) dtw16[i] = (f16)dtw[i];
    if (i < Dm * Ns) {
        int d = i >> 4, n = i & 15;
        a2[n * Dm + d] = -expf(alog[i]) * LOG2E;
    }
}

// per-thread fast-path check: a2r[n] == -(n+1)*LOG2E  (S4D-real init)
__device__ __forceinline__ bool fast_ok(const float* a2r) {
    bool ok = true;
#pragma unroll
    for (int n = 0; n < 16; n++)
        ok = ok && (fabsf(a2r[n] + (float)(n + 1) * LOG2E) <= 3e-5f * (float)(n + 1));
    return ok;
}

// ---------------- GEMM1: x_dbl partials, split-K; also emits x16 ------------
__global__ __launch_bounds__(256) void k_gemm1(const float* __restrict__ x,
                                               const float* __restrict__ w,
                                               float* __restrict__ P,
                                               f16* __restrict__ x16) {
    __shared__ f16 Af[64 * 40];
    __shared__ f16 Bf[160 * 40];
    const int tid = threadIdx.x;
    const int m0 = blockIdx.x * 64;
    const int sk = blockIdx.y;
    const int kbase = sk * KC;
    const int lane = tid & 63;
    const int wv = tid >> 6;
    const int col = lane & 15;
    const int kg = lane >> 4;

    f32x4 acc[10];
#pragma unroll
    for (int i = 0; i < 10; i++) acc[i] = (f32x4){0.f, 0.f, 0.f, 0.f};

    for (int ks = 0; ks < KC / 32; ks++) {
        const int kb = kbase + ks * 32;
        if (ks) __syncthreads();
#pragma unroll
        for (int j = 0; j < 2; j++) {
            int f = tid + j * 256;
            int m = f >> 3, kq = f & 7;
            float4 v = *(const float4*)(x + (size_t)(m0 + m) * Dm + kb + kq * 4);
            f16x4 h = {(f16)v.x, (f16)v.y, (f16)v.z, (f16)v.w};
            *(f16x4*)((char*)Af + m * 80 + kq * 8) = h;
            *(f16x4*)(x16 + (size_t)(m0 + m) * Dm + kb + kq * 4) = h;   // x16 emit
        }
#pragma unroll
        for (int j = 0; j < 5; j++) {
            int f = tid + j * 256;
            int n = f >> 3, kq = f & 7;
            float4 v = *(const float4*)(w + (size_t)n * Dm + kb + kq * 4);
            f16x4 h = {(f16)v.x, (f16)v.y, (f16)v.z, (f16)v.w};
            *(f16x4*)((char*)Bf + n * 80 + kq * 8) = h;
        }
        __syncthreads();
        f16x8 a = *(const f16x8*)((char*)Af + (wv * 16 + col) * 80 + kg * 16);
#pragma unroll
        for (int nf = 0; nf < 10; nf++) {
            f16x8 b = *(const f16x8*)((char*)Bf + (nf * 16 + col) * 80 + kg * 16);
            acc[nf] = __builtin_amdgcn_mfma_f32_16x16x32_f16(a, b, acc[nf], 0, 0, 0);
        }
    }
    float* Pb = P + (size_t)sk * Mm * 160 + (size_t)m0 * 160;
#pragma unroll
    for (int nf = 0; nf < 10; nf++)
#pragma unroll
        for (int r = 0; r < 4; r++) {
            int row = wv * 16 + kg * 4 + r;
            Pb[(size_t)row * 160 + nf * 16 + col] = acc[nf][r];
        }
}

// ---------------- reduce split-K, pack delta_un (fp16) / Bm / Cm ------------
__global__ __launch_bounds__(256) void k_red1(const float* __restrict__ P,
                                              f16* __restrict__ dun,
                                              float* __restrict__ Bm,
                                              float* __restrict__ Cm) {
    int e = blockIdx.x * 256 + threadIdx.x;
    int m = e / 160, c = e % 160;
    float v = 0.f;
#pragma unroll
    for (int s = 0; s < SK; s++) v += P[(size_t)s * Mm * 160 + e];
    if (c < 128)      dun[(size_t)m * Rr + c] = (f16)v;
    else if (c < 144) Bm[(size_t)m * 16 + (c - 128)] = v;
    else              Cm[(size_t)m * 16 + (c - 144)] = v;
}

// ---------------- GEMM2: delta16 = softplus(dun . dtw^T + b) ----------------
__global__ __launch_bounds__(256) void k_gemm2(const f16* __restrict__ dun,
                                               const f16* __restrict__ dtw16,
                                               const float* __restrict__ bias,
                                               f16* __restrict__ delta) {
    __shared__ f16 Ad[64 * 128];
    __shared__ f16 Bd[128 * 128];
    const int tid = threadIdx.x;
    const int lane = tid & 63;
    const int wv = tid >> 6;
    const int m0 = blockIdx.x * 64;
    const int n0 = blockIdx.y * 128;
    const int col = lane & 15;
    const int kg = lane >> 4;
    const int wm = wv & 1, wn = wv >> 1;

    const uint4* gA = (const uint4*)(dun + (size_t)m0 * Rr);
#pragma unroll
    for (int j = 0; j < 4; j++) {
        int slot = tid + j * 256;
        uint4 v = gA[slot];
        int off = slot * 16;
        int row = slot >> 4;
        *(uint4*)((char*)Ad + (off ^ ((row & 7) << 4))) = v;
    }
    const uint4* gB = (const uint4*)(dtw16 + (size_t)n0 * Rr);
#pragma unroll
    for (int j = 0; j < 8; j++) {
        int slot = tid + j * 256;
        uint4 v = gB[slot];
        int off = slot * 16;
        int row = slot >> 4;
        *(uint4*)((char*)Bd + (off ^ ((row & 7) << 4))) = v;
    }
    __syncthreads();

    f32x4 acc[2][4];
#pragma unroll
    for (int i = 0; i < 2; i++)
#pragma unroll
        for (int j = 0; j < 4; j++) acc[i][j] = (f32x4){0.f, 0.f, 0.f, 0.f};

#pragma unroll
    for (int ks = 0; ks < 4; ks++) {
        f16x8 a[2], b[4];
#pragma unroll
        for (int mf = 0; mf < 2; mf++) {
            int row = wm * 32 + mf * 16 + col;
            int off = (row << 8) + ks * 64 + kg * 16;
            a[mf] = *(const f16x8*)((char*)Ad + (off ^ ((row & 7) << 4)));
        }
#pragma unroll
        for (int nf = 0; nf < 4; nf++) {
            int row = wn * 64 + nf * 16 + col;
            int off = (row << 8) + ks * 64 + kg * 16;
            b[nf] = *(const f16x8*)((char*)Bd + (off ^ ((row & 7) << 4)));
        }
#pragma unroll
        for (int mf = 0; mf < 2; mf++)
#pragma unroll
            for (int nf = 0; nf < 4; nf++)
                acc[mf][nf] = __builtin_amdgcn_mfma_f32_16x16x32_f16(a[mf], b[nf], acc[mf][nf], 0, 0, 0);
    }
#pragma unroll
    for (int mf = 0; mf < 2; mf++)
#pragma unroll
        for (int nf = 0; nf < 4; nf++) {
            int gd = n0 + wn * 64 + nf * 16 + col;
            float bv = bias[gd];
#pragma unroll
            for (int r = 0; r < 4; r++) {
                int gm = m0 + wm * 32 + mf * 16 + kg * 4 + r;
                float v = acc[mf][nf][r] + bv;
                float sp = (v > 15.f) ? v : log1pf(expf(v));
                delta[(size_t)gm * Dm + gd] = (f16)sp;
            }
        }
}

// block decode: dblk = bid&7, c = (bid>>3)&63, b = bid>>9
// Sl/S0 layout: [b][c][n][d] fp16 ; dsum layout: [b][c][d] fp32

// ---------------- scan phase 1: LDS-staged chunk summaries ------------------
__global__ __launch_bounds__(256, 4) void k_scan1(const f16* __restrict__ delta,
                                                  const f16* __restrict__ x16,
                                                  const float* __restrict__ Bm,
                                                  const float* __restrict__ a2g,
                                                  f16* __restrict__ Sl,
                                                  float* __restrict__ dsumO) {
    __shared__ f16 dl[LC * 256];      // 16 KB
    __shared__ f16 xl[LC * 256];      // 16 KB
    __shared__ float bcl[LC * 16];    // 2 KB (B rows)

    const int tid = threadIdx.x;
    const int bid = blockIdx.x;
    const int dblk = bid & 7;
    const int c = (bid >> 3) & (NC - 1);
    const int b = bid >> 9;
    const int d0 = dblk * 256;
    const int d = d0 + tid;
    const int row0 = b * Ls + c * LC;

    if (tid < LC * 4) {
        int l = tid >> 2, q = tid & 3;
        *(float4*)&bcl[l * 16 + q * 4] = *(const float4*)(Bm + (size_t)(row0 + l) * 16 + q * 4);
    }
    {
        const char* srcD = (const char*)(delta + (size_t)row0 * Dm + d0);
        const char* srcX = (const char*)(x16 + (size_t)row0 * Dm + d0);
#pragma unroll
        for (int j = 0; j < 4; j++) {
            int slot = tid + j * 256;         // 1024 x 16B
            int l = slot >> 5, o = slot & 31;
            uint4 vD = *(const uint4*)(srcD + (size_t)l * Dm * 2 + o * 16);
            uint4 vX = *(const uint4*)(srcX + (size_t)l * Dm * 2 + o * 16);
            *(uint4*)((char*)dl + slot * 16) = vD;
            *(uint4*)((char*)xl + slot * 16) = vX;
        }
    }
    float a2r[16];
#pragma unroll
    for (int n = 0; n < 16; n++) a2r[n] = a2g[(size_t)n * Dm + d];
    const bool fastp = fast_ok(a2r);

    float s[16];
#pragma unroll
    for (int n = 0; n < 16; n++) s[n] = 0.f;
    float dsum = 0.f;
    __syncthreads();

    if (fastp) {
#pragma unroll 4
        for (int i = 0; i < LC; i++) {
            float dc = (float)dl[i * 256 + tid];
            float xc = (float)xl[i * 256 + tid];
            float dx = dc * xc;
            dsum += dc;
            float w1 = exp2f(dc * (-LOG2E));       // e^{-dc}
            float w2 = w1 * w1, w3 = w2 * w1, w4 = w2 * w2;
            float w8 = w4 * w4, w12 = w8 * w4;
            float4 b0 = *(const float4*)&bcl[i * 16 + 0];
            float4 b1 = *(const float4*)&bcl[i * 16 + 4];
            float4 b2 = *(const float4*)&bcl[i * 16 + 8];
            float4 b3 = *(const float4*)&bcl[i * 16 + 12];
            s[0] = fmaf(w1, s[0], dx * b0.x);  s[1] = fmaf(w2, s[1], dx * b0.y);
            s[2] = fmaf(w3, s[2], dx * b0.z);  s[3] = fmaf(w4, s[3], dx * b0.w);
            s[4] = fmaf(w4 * w1, s[4], dx * b1.x);  s[5] = fmaf(w4 * w2, s[5], dx * b1.y);
            s[6] = fmaf(w4 * w3, s[6], dx * b1.z);  s[7] = fmaf(w8, s[7], dx * b1.w);
            s[8] = fmaf(w8 * w1, s[8], dx * b2.x);  s[9] = fmaf(w8 * w2, s[9], dx * b2.y);
            s[10] = fmaf(w8 * w3, s[10], dx * b2.z); s[11] = fmaf(w12, s[11], dx * b2.w);
            s[12] = fmaf(w12 * w1, s[12], dx * b3.x); s[13] = fmaf(w12 * w2, s[13], dx * b3.y);
            s[14] = fmaf(w12 * w3, s[14], dx * b3.z); s[15] = fmaf(w12 * w4, s[15], dx * b3.w);
        }
    } else {
        for (int i = 0; i < LC; i++) {
            float dc = (float)dl[i * 256 + tid];
            float xc = (float)xl[i * 256 + tid];
            float dx = dc * xc;
            dsum += dc;
#pragma unroll
            for (int n = 0; n < 16; n++)
                s[n] = fmaf(exp2f(dc * a2r[n]), s[n], dx * bcl[i * 16 + n]);
        }
    }
    const size_t ob = ((size_t)(b * NC + c) * 16) * Dm + d;
#pragma unroll
    for (int n = 0; n < 16; n++) Sl[ob + (size_t)n * Dm] = (f16)s[n];
    dsumO[(size_t)(b * NC + c) * Dm + d] = dsum;
}

// ---------------- scan phase 2: chunk combine (recompute Ap from dsum) ------
__global__ __launch_bounds__(256) void k_scan2(const float* __restrict__ dsum,
                                               const f16* __restrict__ Sl,
                                               const float* __restrict__ a2g,
                                               f16* __restrict__ S0) {
    int e = blockIdx.x * 256 + threadIdx.x;   // < Bb*16*Dm
    int d = e & (Dm - 1);
    int n = (e >> 11) & 15;
    int b = e >> 15;
    float a2r = a2g[(size_t)n * Dm + d];
    size_t baseS = ((size_t)(b * NC) * 16 + n) * Dm + d;
    size_t baseD = (size_t)(b * NC) * Dm + d;
    const size_t cs = (size_t)16 * Dm;
    float s = 0.f;
    for (int cg = 0; cg < NC / 8; cg++) {
        float dsb[8], slb[8];
#pragma unroll
        for (int j = 0; j < 8; j++) {
            dsb[j] = dsum[baseD + (size_t)(cg * 8 + j) * Dm];
            slb[j] = (float)Sl[baseS + (size_t)(cg * 8 + j) * cs];
        }
#pragma unroll
        for (int j = 0; j < 8; j++) {
            S0[baseS + (size_t)(cg * 8 + j) * cs] = (f16)s;
            s = fmaf(exp2f(dsb[j] * a2r), s, slb[j]);
        }
    }
}

// ---------------- scan phase 3: LDS-staged rescan, emit y -------------------
__global__ __launch_bounds__(256, 4) void k_scan3(const f16* __restrict__ delta,
                                                  const f16* __restrict__ x16,
                                                  const float* __restrict__ Bm,
                                                  const float* __restrict__ Cm,
                                                  const float* __restrict__ a2g,
                                                  const f16* __restrict__ S0,
                                                  const float* __restrict__ Dpar,
                                                  float* __restrict__ out) {
    __shared__ f16 dl[LC * 256];      // 16 KB
    __shared__ f16 xl[LC * 256];      // 16 KB
    __shared__ float bcl[LC * 32];    // 4 KB (B row | C row)

    const int tid = threadIdx.x;
    const int bid = blockIdx.x;
    const int dblk = bid & 7;
    const int c = (bid >> 3) & (NC - 1);
    const int b = bid >> 9;
    const int d0 = dblk * 256;
    const int d = d0 + tid;
    const int row0 = b * Ls + c * LC;

    if (tid < LC * 4) {
        int l = tid >> 2, q = tid & 3;
        *(float4*)&bcl[l * 32 + q * 4] = *(const float4*)(Bm + (size_t)(row0 + l) * 16 + q * 4);
    } else if (tid < LC * 8) {
        int t = tid - LC * 4;
        int l = t >> 2, q = t & 3;
        *(float4*)&bcl[l * 32 + 16 + q * 4] = *(const float4*)(Cm + (size_t)(row0 + l) * 16 + q * 4);
    }
    {
        const char* srcD = (const char*)(delta + (size_t)row0 * Dm + d0);
        const char* srcX = (const char*)(x16 + (size_t)row0 * Dm + d0);
#pragma unroll
        for (int j = 0; j < 4; j++) {
            int slot = tid + j * 256;
            int l = slot >> 5, o = slot & 31;
            uint4 vD = *(const uint4*)(srcD + (size_t)l * Dm * 2 + o * 16);
            uint4 vX = *(const uint4*)(srcX + (size_t)l * Dm * 2 + o * 16);
            *(uint4*)((char*)dl + slot * 16) = vD;
            *(uint4*)((char*)xl + slot * 16) = vX;
        }
    }
    float a2r[16];
#pragma unroll
    for (int n = 0; n < 16; n++) a2r[n] = a2g[(size_t)n * Dm + d];
    const bool fastp = fast_ok(a2r);

    const size_t ob = ((size_t)(b * NC + c) * 16) * Dm + d;
    float s[16];
#pragma unroll
    for (int n = 0; n < 16; n++) s[n] = (float)S0[ob + (size_t)n * Dm];
    const float Dp = Dpar[d];
    float* optr = out + (size_t)row0 * Dm + d;
    __syncthreads();

    if (fastp) {
#pragma unroll 4
        for (int i = 0; i < LC; i++) {
            float dc = (float)dl[i * 256 + tid];
            float xc = (float)xl[i * 256 + tid];
            float dx = dc * xc;
            float w1 = exp2f(dc * (-LOG2E));
            float w2 = w1 * w1, w3 = w2 * w1, w4 = w2 * w2;
            float w8 = w4 * w4, w12 = w8 * w4;
            float4 b0 = *(const float4*)&bcl[i * 32 + 0];
            float4 b1 = *(const float4*)&bcl[i * 32 + 4];
            float4 b2 = *(const float4*)&bcl[i * 32 + 8];
            float4 b3 = *(const float4*)&bcl[i * 32 + 12];
            float4 c0 = *(const float4*)&bcl[i * 32 + 16];
            float4 c1 = *(const float4*)&bcl[i * 32 + 20];
            float4 c2 = *(const float4*)&bcl[i * 32 + 24];
            float4 c3 = *(const float4*)&bcl[i * 32 + 28];
            s[0] = fmaf(w1, s[0], dx * b0.x);  s[1] = fmaf(w2, s[1], dx * b0.y);
            s[2] = fmaf(w3, s[2], dx * b0.z);  s[3] = fmaf(w4, s[3], dx * b0.w);
            s[4] = fmaf(w4 * w1, s[4], dx * b1.x);  s[5] = fmaf(w4 * w2, s[5], dx * b1.y);
            s[6] = fmaf(w4 * w3, s[6], dx * b1.z);  s[7] = fmaf(w8, s[7], dx * b1.w);
            s[8] = fmaf(w8 * w1, s[8], dx * b2.x);  s[9] = fmaf(w8 * w2, s[9], dx * b2.y);
            s[10] = fmaf(w8 * w3, s[10], dx * b2.z); s[11] = fmaf(w12, s[11], dx * b2.w);
            s[12] = fmaf(w12 * w1, s[12], dx * b3.x); s[13] = fmaf(w12 * w2, s[13], dx * b3.y);
            s[14] = fmaf(w12 * w3, s[14], dx * b3.z); s[15] = fmaf(w12 * w4, s[15], dx * b3.w);
            float y0 = s[0] * c0.x, y1 = s[1] * c0.y, y2 = s[2] * c0.z, y3 = s[3] * c0.w;
            y0 = fmaf(s[4], c1.x, y0); y1 = fmaf(s[5], c1.y, y1);
            y2 = fmaf(s[6], c1.z, y2); y3 = fmaf(s[7], c1.w, y3);
            y0 = fmaf(s[8], c2.x, y0); y1 = fmaf(s[9], c2.y, y1);
            y2 = fmaf(s[10], c2.z, y2); y3 = fmaf(s[11], c2.w, y3);
            y0 = fmaf(s[12], c3.x, y0); y1 = fmaf(s[13], c3.y, y1);
            y2 = fmaf(s[14], c3.z, y2); y3 = fmaf(s[15], c3.w, y3);
            optr[(size_t)i * Dm] = fmaf(xc, Dp, (y0 + y1) + (y2 + y3));
        }
    } else {
        for (int i = 0; i < LC; i++) {
            float dc = (float)dl[i * 256 + tid];
            float xc = (float)xl[i * 256 + tid];
            float dx = dc * xc;
            float yv = 0.f;
#pragma unroll
            for (int n = 0; n < 16; n++) {
                s[n] = fmaf(exp2f(dc * a2r[n]), s[n], dx * bcl[i * 32 + n]);
                yv = fmaf(s[n], bcl[i * 32 + 16 + n], yv);
            }
            optr[(size_t)i * Dm] = fmaf(xc, Dp, yv);
        }
    }
}

// ---------------- host launcher ---------------------------------------------
extern "C" void kernel_launch(void* const* d_in, const int* in_sizes, int n_in,
                              void* d_out, int out_size, void* d_ws, size_t ws_size,
                              hipStream_t stream) {
    const float* x    = (const float*)d_in[0];
    const float* xw   = (const float*)d_in[1];
    const float* dtw  = (const float*)d_in[2];
    const float* dtb  = (const float*)d_in[3];
    const float* alog = (const float*)d_in[4];
    const float* dpar = (const float*)d_in[5];
    float* out = (float*)d_out;

    char* ws = (char*)d_ws;
    size_t off = 0;
    auto alloc = [&](size_t bytes) {
        char* p = ws + off;
        off += (bytes + 255) & ~(size_t)255;
        return p;
    };
    f16*   dun    = (f16*)  alloc((size_t)Mm * Rr * 2);             // 1 MB
    float* BmA    = (float*)alloc((size_t)Mm * 16 * 4);             // 256 KB
    float* CmA    = (float*)alloc((size_t)Mm * 16 * 4);             // 256 KB
    float* Pp     = (float*)alloc((size_t)SK * Mm * 160 * 4);       // 21 MB
    f16*   deltaA = (f16*)  alloc((size_t)Mm * Dm * 2);             // 16.8 MB
    f16*   x16A   = (f16*)  alloc((size_t)Mm * Dm * 2);             // 16.8 MB
    f16*   SlA    = (f16*)  alloc((size_t)Bb * NC * 16 * Dm * 2);   // 8 MB
    f16*   S0A    = (f16*)  alloc((size_t)Bb * NC * 16 * Dm * 2);   // 8 MB
    float* dsumA  = (float*)alloc((size_t)Bb * NC * Dm * 4);        // 1 MB
    f16*   dtw16  = (f16*)  alloc((size_t)Dm * Rr * 2);             // 512 KB
    float* a2A    = (float*)alloc((size_t)Ns * Dm * 4);             // 128 KB

    hipLaunchKernelGGL(k_prep, dim3((Dm * Rr) / 256), dim3(256), 0, stream,
                       dtw, alog, dtw16, a2A);
    hipLaunchKernelGGL(k_gemm1, dim3(Mm / 64, SK), dim3(256), 0, stream,
                       x, xw, Pp, x16A);
    hipLaunchKernelGGL(k_red1, dim3((Mm * 160) / 256), dim3(256), 0, stream,
                       Pp, dun, BmA, CmA);
    hipLaunchKernelGGL(k_gemm2, dim3(Mm / 64, Dm / 128), dim3(256), 0, stream,
                       dun, dtw16, dtb, deltaA);
    hipLaunchKernelGGL(k_scan1, dim3(Bb * 8 * NC), dim3(256), 0, stream,
                       deltaA, x16A, BmA, a2A, SlA, dsumA);
    hipLaunchKernelGGL(k_scan2, dim3((Bb * 16 * Dm) / 256), dim3(256), 0, stream,
                       dsumA, SlA, a2A, S0A);
    hipLaunchKernelGGL(k_scan3, dim3(Bb * 8 * NC), dim3(256), 0, stream,
                       deltaA, x16A, BmA, CmA, a2A, S0A, dpar, out);
}